// Round 14
// baseline (303.138 us; speedup 1.0000x reference)
//
#include <hip/hip_runtime.h>
#include <hip/hip_bf16.h>
#include <math.h>

#define B_   4
#define N_   4096
#define K_   16
#define DP_  128
#define DM_  256
#define NPTS (B_ * N_)
#define SEG_ 16
#define CAND_ (N_ / SEG_)   // 256 candidates per segment

typedef unsigned int u32;
typedef unsigned char u8;
typedef _Float16 f16;
typedef __attribute__((ext_vector_type(2))) __fp16 h2;     // matches cvt_pkrtz ABI
typedef __attribute__((ext_vector_type(8))) _Float16 f16x8; // MFMA operand
typedef __attribute__((ext_vector_type(4))) float floatx4;

static __device__ __forceinline__ h2 pkrtz(float a, float b) {
    return __builtin_amdgcn_cvt_pkrtz(a, b);
}
static __device__ __forceinline__ u32 asu32(h2 h) { return __builtin_bit_cast(u32, h); }
static __device__ __forceinline__ h2 ash2(u32 u) { return __builtin_bit_cast(h2, u); }

// ---- bitonic primitives on u32 registers ----
#define CEXA(x, y) { u32 _lo = min(x, y); y = max(x, y); x = _lo; }   // x<=y
#define CEXD(x, y) { u32 _hi = max(x, y); y = min(x, y); x = _hi; }   // x>=y

static __device__ __forceinline__ void sort16_desc(u32 c[16]) {
    CEXD(c[0],c[1]);  CEXA(c[2],c[3]);  CEXD(c[4],c[5]);  CEXA(c[6],c[7]);
    CEXD(c[8],c[9]);  CEXA(c[10],c[11]); CEXD(c[12],c[13]); CEXA(c[14],c[15]);

    CEXD(c[0],c[2]);  CEXD(c[1],c[3]);  CEXA(c[4],c[6]);  CEXA(c[5],c[7]);
    CEXD(c[8],c[10]); CEXD(c[9],c[11]); CEXA(c[12],c[14]); CEXA(c[13],c[15]);
    CEXD(c[0],c[1]);  CEXD(c[2],c[3]);  CEXA(c[4],c[5]);  CEXA(c[6],c[7]);
    CEXD(c[8],c[9]);  CEXD(c[10],c[11]); CEXA(c[12],c[13]); CEXA(c[14],c[15]);

    CEXD(c[0],c[4]);  CEXD(c[1],c[5]);  CEXD(c[2],c[6]);  CEXD(c[3],c[7]);
    CEXA(c[8],c[12]); CEXA(c[9],c[13]); CEXA(c[10],c[14]); CEXA(c[11],c[15]);
    CEXD(c[0],c[2]);  CEXD(c[1],c[3]);  CEXD(c[4],c[6]);  CEXD(c[5],c[7]);
    CEXA(c[8],c[10]); CEXA(c[9],c[11]); CEXA(c[12],c[14]); CEXA(c[13],c[15]);
    CEXD(c[0],c[1]);  CEXD(c[2],c[3]);  CEXD(c[4],c[5]);  CEXD(c[6],c[7]);
    CEXA(c[8],c[9]);  CEXA(c[10],c[11]); CEXA(c[12],c[13]); CEXA(c[14],c[15]);

    CEXD(c[0],c[8]);  CEXD(c[1],c[9]);  CEXD(c[2],c[10]); CEXD(c[3],c[11]);
    CEXD(c[4],c[12]); CEXD(c[5],c[13]); CEXD(c[6],c[14]); CEXD(c[7],c[15]);
    CEXD(c[0],c[4]);  CEXD(c[1],c[5]);  CEXD(c[2],c[6]);  CEXD(c[3],c[7]);
    CEXD(c[8],c[12]); CEXD(c[9],c[13]); CEXD(c[10],c[14]); CEXD(c[11],c[15]);
    CEXD(c[0],c[2]);  CEXD(c[1],c[3]);  CEXD(c[4],c[6]);  CEXD(c[5],c[7]);
    CEXD(c[8],c[10]); CEXD(c[9],c[11]); CEXD(c[12],c[14]); CEXD(c[13],c[15]);
    CEXD(c[0],c[1]);  CEXD(c[2],c[3]);  CEXD(c[4],c[5]);  CEXD(c[6],c[7]);
    CEXD(c[8],c[9]);  CEXD(c[10],c[11]); CEXD(c[12],c[13]); CEXD(c[14],c[15]);
}

static __device__ __forceinline__ void remerge16_asc(u32 L[16]) {
    CEXA(L[0],L[8]);  CEXA(L[1],L[9]);  CEXA(L[2],L[10]); CEXA(L[3],L[11]);
    CEXA(L[4],L[12]); CEXA(L[5],L[13]); CEXA(L[6],L[14]); CEXA(L[7],L[15]);
    CEXA(L[0],L[4]);  CEXA(L[1],L[5]);  CEXA(L[2],L[6]);  CEXA(L[3],L[7]);
    CEXA(L[8],L[12]); CEXA(L[9],L[13]); CEXA(L[10],L[14]); CEXA(L[11],L[15]);
    CEXA(L[0],L[2]);  CEXA(L[1],L[3]);  CEXA(L[4],L[6]);  CEXA(L[5],L[7]);
    CEXA(L[8],L[10]); CEXA(L[9],L[11]); CEXA(L[12],L[14]); CEXA(L[13],L[15]);
    CEXA(L[0],L[1]);  CEXA(L[2],L[3]);  CEXA(L[4],L[5]);  CEXA(L[6],L[7]);
    CEXA(L[8],L[9]);  CEXA(L[10],L[11]); CEXA(L[12],L[13]); CEXA(L[14],L[15]);
}

// ---------------- GEMM tile as device fn (C[M,N] = A@Bt^T +bias +addC) ----------------
static __device__ void gemm_tile(f16* As, f16* Bs,
    const f16* __restrict__ A, const f16* __restrict__ Bt,
    const float* __restrict__ bias, const float* __restrict__ addC,
    float* __restrict__ CT, f16* __restrict__ Cb,
    int M, int N, int K, int ldc, int bx, int by)
{
    const int tid = threadIdx.x;
    const int m0 = by * 128, n0 = bx * 128;
    const int w = tid >> 6, l = tid & 63;
    const int wm = (w >> 1) * 64, wn = (w & 1) * 64;
    const int fm = l & 15, kq = l >> 4;

    floatx4 acc[4][4];
#pragma unroll
    for (int i = 0; i < 4; ++i)
#pragma unroll
        for (int j = 0; j < 4; ++j)
            acc[i][j] = (floatx4){0.0f, 0.0f, 0.0f, 0.0f};

    for (int k0 = 0; k0 < K; k0 += 32) {
        __syncthreads();
#pragma unroll
        for (int c = 0; c < 2; ++c) {
            const int li = tid + c * 256;
            const int row = li >> 2, part = li & 3;
            *(uint4*)&As[row * 32 + part * 8] =
                *(const uint4*)&A[(size_t)(m0 + row) * K + k0 + part * 8];
            *(uint4*)&Bs[row * 32 + part * 8] =
                *(const uint4*)&Bt[(size_t)(n0 + row) * K + k0 + part * 8];
        }
        __syncthreads();
        f16x8 af[4], bf[4];
#pragma unroll
        for (int i = 0; i < 4; ++i)
            af[i] = *(const f16x8*)&As[(wm + i * 16 + fm) * 32 + kq * 8];
#pragma unroll
        for (int j = 0; j < 4; ++j)
            bf[j] = *(const f16x8*)&Bs[(wn + j * 16 + fm) * 32 + kq * 8];
#pragma unroll
        for (int i = 0; i < 4; ++i)
#pragma unroll
            for (int j = 0; j < 4; ++j)
                acc[i][j] = __builtin_amdgcn_mfma_f32_16x16x32_f16(af[i], bf[j], acc[i][j], 0, 0, 0);
    }

#pragma unroll
    for (int i = 0; i < 4; ++i) {
#pragma unroll
        for (int j = 0; j < 4; ++j) {
            const int col = n0 + wn + j * 16 + fm;
            const int rowb = m0 + wm + i * 16 + kq * 4;
            float4 vv;
#pragma unroll
            for (int r = 0; r < 4; ++r) {
                const int m = rowb + r;
                float v = acc[i][j][r];
                if (bias) v += bias[col];
                if (addC) v += addC[(size_t)m * ldc + col];
                ((float*)&vv)[r] = v;
            }
            if (CT) {   // rows rowb..rowb+3 consecutive n in one batch: transposed store
                const int bb = rowb >> 12;
                *(float4*)&CT[(size_t)(bb * DP_ + col) * N_ + (rowb & (N_ - 1))] = vv;
            } else if (Cb) {
#pragma unroll
                for (int r = 0; r < 4; ++r)
                    Cb[(size_t)(rowb + r) * ldc + col] = (f16)((float*)&vv)[r];
            }
        }
    }
}

// plain GEMM wrapper (used for the final out-GEMM)
__global__ __launch_bounds__(256) void gemm_f16_kernel(
    const f16* __restrict__ A, const f16* __restrict__ Bt,
    const float* __restrict__ bias, const float* __restrict__ addC,
    float* __restrict__ CT, f16* __restrict__ Cb,
    int M, int N, int K, int ldc)
{
    __shared__ __align__(16) f16 As[128 * 32];
    __shared__ __align__(16) f16 Bs[128 * 32];
    gemm_tile(As, Bs, A, Bt, bias, addC, CT, Cb, M, N, K, ldc, blockIdx.x, blockIdx.y);
}

// ---------------- KNN part body ----------------
static __device__ void knn_part_body(float4* sc, const float* __restrict__ xyz,
                                     u32* __restrict__ part, int id)
{
    const int xblk = id & 15;            // N_/256 = 16
    const int s = (id >> 4) & 15;        // SEG_ = 16
    const int b = id >> 8;               // B_ = 4
    const int n = xblk * 256 + threadIdx.x;
    const float* xb = xyz + (size_t)b * N_ * 3;
    const float xn0 = xb[n * 3 + 0], xn1 = xb[n * 3 + 1], xn2 = xb[n * 3 + 2];

    {
        const int m = s * CAND_ + threadIdx.x;   // CAND_ == 256 == blockDim.x
        const float a0 = xb[m * 3 + 0];
        const float a1 = xb[m * 3 + 1];
        const float a2 = xb[m * 3 + 2];
        sc[threadIdx.x] = make_float4(a0, a1, a2, 0.5f * (a0 * a0 + a1 * a1 + a2 * a2));
    }
    __syncthreads();

    u32 L[16];
#pragma unroll
    for (int i = 0; i < 16; ++i) L[i] = 0xFFFFFFFFu;

    const u32 ibase = (u32)(s * CAND_);
    for (int m0 = 0; m0 < CAND_; m0 += 16) {
        u32 c[16];
#pragma unroll
        for (int t = 0; t < 16; ++t) {
            const float4 cc = sc[m0 + t];
            const float dot = xn0 * cc.x + xn1 * cc.y + xn2 * cc.z;
            const float e = cc.w - dot;       // rank-equivalent to d2 (monotone shift)
            const int ib = __float_as_int(e);
            const u32 tk = (u32)ib ^ (u32)((ib >> 31) | 0x80000000);
            c[t] = (tk & 0xFFFFF000u) | (ibase + (u32)(m0 + t));
        }
        sort16_desc(c);
#pragma unroll
        for (int i = 0; i < 16; ++i) L[i] = min(L[i], c[i]);
        remerge16_asc(L);
    }

    const int p = b * N_ + n;
#pragma unroll
    for (int j = 0; j < 16; ++j)
        part[(size_t)(s * 16 + j) * NPTS + p] = L[j];
}

// ---------------- FUSED: qkv GEMM (blocks 0..1023) + knn_part (1024..2047) ----------------
__global__ __launch_bounds__(256) void fused_main_kernel(
    const f16* __restrict__ featb, const f16* __restrict__ WallT,
    const float* __restrict__ b_all, f16* __restrict__ qkv,
    const float* __restrict__ xyz, u32* __restrict__ part)
{
    __shared__ __align__(16) char smem[32768];
    const int id = blockIdx.x;
    if (id < 1024) {   // qkv: M=NPTS, N=1024, K=DP_, grid (8 n-tiles, 128 m-tiles)
        f16* As = (f16*)smem;
        f16* Bs = (f16*)(smem + 8192);
        gemm_tile(As, Bs, featb, WallT, b_all, nullptr, nullptr, qkv,
                  NPTS, 1024, DP_, 1024, id & 7, id >> 3);
    } else {
        knn_part_body((float4*)smem, xyz, part, id - 1024);
    }
}

// ---------------- merge A body + kv8 body, FUSED ----------------
static __device__ void knn_mergeA_body(const u32* __restrict__ part, u32* __restrict__ m4,
                                       int id)
{
    const int px = id & 63, g = id >> 6;                 // 64 x 4
    const int p = px * 256 + threadIdx.x;

    u32 L[16];
#pragma unroll
    for (int i = 0; i < 16; ++i) L[i] = 0xFFFFFFFFu;

    for (int s = g * 4; s < g * 4 + 4; ++s) {
        u32 seg[16];
#pragma unroll
        for (int j = 0; j < 16; ++j)
            seg[j] = part[(size_t)(s * 16 + j) * NPTS + p];
#pragma unroll
        for (int i = 0; i < 16; ++i) L[i] = min(L[i], seg[15 - i]);
        remerge16_asc(L);
    }
#pragma unroll
    for (int j = 0; j < 16; ++j)
        m4[(size_t)(g * 16 + j) * NPTS + p] = L[j];
}

static __device__ void kv8_body(const f16* __restrict__ qkv, u8* __restrict__ kv8, int id)
{
    const int t = id * 256 + threadIdx.x;   // 0 .. NPTS*64-1
    const int p = t >> 6, g = t & 63;
    const uint4 kv = *(const uint4*)(qkv + (size_t)p * 1024 + 256 + g * 8);
    const h2 k01 = ash2(kv.x), k23 = ash2(kv.y), v01 = ash2(kv.z), v23 = ash2(kv.w);
    int lo = 0, hi = 0;
    lo = __builtin_amdgcn_cvt_pk_fp8_f32((float)k01.x, (float)k01.y, lo, false);
    lo = __builtin_amdgcn_cvt_pk_fp8_f32((float)k23.x, (float)k23.y, lo, true);
    hi = __builtin_amdgcn_cvt_pk_fp8_f32((float)v01.x, (float)v01.y, hi, false);
    hi = __builtin_amdgcn_cvt_pk_fp8_f32((float)v23.x, (float)v23.y, hi, true);
    *(uint2*)(kv8 + (size_t)p * 512 + g * 8) = make_uint2((u32)lo, (u32)hi);
}

__global__ __launch_bounds__(256) void fused_m4kv8_kernel(
    const f16* __restrict__ qkv, u8* __restrict__ kv8,
    const u32* __restrict__ part, u32* __restrict__ m4)
{
    const int id = blockIdx.x;
    if (id < NPTS * 64 / 256) kv8_body(qkv, kv8, id);
    else                      knn_mergeA_body(part, m4, id - NPTS * 64 / 256);
}

// ---------------- KNN merge stage B: 4 sorted lists -> final top-16 indices ----------------
__global__ __launch_bounds__(256, 1) void knn_mergeB_kernel(const u32* __restrict__ m4,
                                                            int* __restrict__ knn_idx)
{
    const int p = blockIdx.x * 256 + threadIdx.x;
    const int b = p >> 12;

    u32 L[16];
#pragma unroll
    for (int i = 0; i < 16; ++i) L[i] = 0xFFFFFFFFu;

    for (int g = 0; g < 4; ++g) {
        u32 seg[16];
#pragma unroll
        for (int j = 0; j < 16; ++j)
            seg[j] = m4[(size_t)(g * 16 + j) * NPTS + p];
#pragma unroll
        for (int i = 0; i < 16; ++i) L[i] = min(L[i], seg[15 - i]);
        remerge16_asc(L);
    }

    int* o = knn_idx + (size_t)p * K_;
#pragma unroll
    for (int i = 0; i < 16; ++i) o[i] = b * N_ + (int)(L[i] & 0xFFFu);
}

// ---------------- one-shot prep: weight transpose-casts + straight casts (f16) ----------------
// k/v rows of catW INTERLEAVED: k-col c -> row 256+8*(c/4)+(c%4); v-col c -> +4.
__global__ __launch_bounds__(256) void prep_kernel(
    const float* __restrict__ wq, const float* __restrict__ wk, const float* __restrict__ wv,
    const float* __restrict__ fd2, const float* __restrict__ fc1, const float* __restrict__ fc2,
    const float* __restrict__ feat,
    f16* __restrict__ catW, f16* __restrict__ fc2T, f16* __restrict__ bt2,
    f16* __restrict__ fd2c, f16* __restrict__ wqc, f16* __restrict__ fc1c,
    f16* __restrict__ featb)
{
    __shared__ float t[32][33];
    const int job = blockIdx.z;
    const int tid = threadIdx.x;

    if (job < 4) {
        const float* in; int R, C;
        switch (job) {
            case 0: in = wq;  R = DM_; C = DM_; break;
            case 1: in = wk;  R = DM_; C = DM_; break;
            case 2: in = wv;  R = DM_; C = DM_; break;
            default: in = fc2; R = DM_; C = DP_; break;
        }
        const int c0 = blockIdx.x * 32, r0 = blockIdx.y * 32;
        if (c0 >= C || r0 >= R) return;
        const int lx = tid & 31, ly = tid >> 5;
#pragma unroll
        for (int i = 0; i < 32; i += 8)
            t[ly + i][lx] = in[(size_t)(r0 + ly + i) * C + c0 + lx];
        __syncthreads();
#pragma unroll
        for (int i = 0; i < 32; i += 8) {
            const int c = c0 + ly + i;
            const f16 v = (f16)t[lx][ly + i];
            int n;
            switch (job) {
                case 0: n = c; break;
                case 1: n = 256 + ((c >> 2) << 3) + (c & 3); break;
                case 2: n = 256 + ((c >> 2) << 3) + 4 + (c & 3); break;
                default: n = -1; break;
            }
            if (job < 3) {
                catW[(size_t)n * DM_ + r0 + lx] = v;
            } else {
                fc2T[(size_t)c * DM_ + r0 + lx] = v;
                bt2[(size_t)c * 512 + 256 + r0 + lx] = v;
            }
        }
    } else {
        const int bid = blockIdx.y * 8 + blockIdx.x;
        const int tId = bid * 256 + tid;
        const float* in; f16* outp; int n4;
        if (job == 4)      { in = fd2;  outp = fd2c;  n4 = (DM_ * DM_) / 4; }
        else if (job == 5) { in = wq;   outp = wqc;   n4 = (DM_ * DM_) / 4; }
        else if (job == 6) { in = fc1;  outp = fc1c;  n4 = (DP_ * DM_) / 4; }
        else               { in = feat; outp = featb; n4 = (NPTS * DP_) / 4; }
        for (int i = tId; i < n4; i += 16384) {
            const float4 v = ((const float4*)in)[i];
            const u32 lo = asu32(pkrtz(v.x, v.y));
            const u32 hi = asu32(pkrtz(v.z, v.w));
            ((uint2*)outp)[i] = make_uint2(lo, hi);
        }
    }
}

// ---------------- fused small GEMMs 1: wqp (4 tiles) + bt2 (2 tiles) ----------------
__global__ __launch_bounds__(256) void fused_small1_kernel(
    const f16* __restrict__ fd2c, const f16* __restrict__ wqc,
    f16* __restrict__ catWqp,                   // catW + 768*256
    const f16* __restrict__ fc2T, f16* __restrict__ bt2)
{
    __shared__ __align__(16) f16 As[128 * 32];
    __shared__ __align__(16) f16 Bs[128 * 32];
    const int id = blockIdx.x;
    if (id < 4)
        gemm_tile(As, Bs, fd2c, wqc, nullptr, nullptr, nullptr, catWqp,
                  DM_, DM_, DM_, DM_, id & 1, id >> 1);
    else
        gemm_tile(As, Bs, fc2T, fd2c, nullptr, nullptr, nullptr, bt2,
                  DP_, DM_, DM_, 512, id - 4, 0);
}

// ---------------- fused small GEMMs 2: WallT (8 tiles) + folded biases (5 blocks) ----------------
__global__ __launch_bounds__(256) void fused_small2_kernel(
    const f16* __restrict__ catW, const f16* __restrict__ fc1c, f16* __restrict__ WallT,
    const float* __restrict__ fc1_b, const float* __restrict__ fd2_b,
    const float* __restrict__ fc2_w, const float* __restrict__ fc2_b,
    float* __restrict__ b_all, float* __restrict__ bias2)
{
    __shared__ __align__(16) f16 As[128 * 32];
    __shared__ __align__(16) f16 Bs[128 * 32];
    const int id = blockIdx.x;
    const int tid = threadIdx.x;
    if (id < 8) {
        gemm_tile(As, Bs, catW, fc1c, nullptr, nullptr, nullptr, WallT,
                  1024, DP_, DM_, DP_, 0, id);
    } else if (id < 12) {
        const int n = (id - 8) * 256 + tid;
        float s = 0.0f;
        for (int j = 0; j < DM_; ++j)
            s += fc1_b[j] * (float)catW[(size_t)n * DM_ + j];
        b_all[n] = s;
    } else if (tid < DP_) {
        float s = fc2_b[tid];
        for (int t = 0; t < DM_; ++t)
            s += fd2_b[t] * fc2_w[(size_t)t * DP_ + tid];
        bias2[tid] = s;
    }
}

// ---------------- fused attention: one WAVE per point; fp8 kv gather (8 B/lane/neighbor) ----
__global__ __launch_bounds__(256, 1) void attn_kernel(
    const float* __restrict__ xyz, const f16* __restrict__ qkv,
    const u8* __restrict__ kv8, const int* __restrict__ knn_idx,
    const float* __restrict__ fd1_w, const float* __restrict__ fd1_b,
    const float* __restrict__ fd2_b,
    f16* __restrict__ ab)
{
    const int wave = threadIdx.x >> 6, l = threadIdx.x & 63;
    const int p = blockIdx.x * 4 + wave;
    const int c0 = l * 4;

    int gi = 0; float dx = 0.0f, dy = 0.0f, dz = 0.0f;
    if (l < 16) {
        gi = knn_idx[p * K_ + l];
        dx = xyz[(size_t)p * 3 + 0] - xyz[(size_t)gi * 3 + 0];
        dy = xyz[(size_t)p * 3 + 1] - xyz[(size_t)gi * 3 + 1];
        dz = xyz[(size_t)p * 3 + 2] - xyz[(size_t)gi * 3 + 2];
    }

    // prefetch ALL 16 neighbor kv8 rows (independent 8B loads), pin above compute
    uint2 kvr8[16];
#pragma unroll
    for (int k = 0; k < 16; ++k) {
        const int gik = __shfl(gi, k);
        kvr8[k] = *(const uint2*)(kv8 + (size_t)gik * 512 + l * 8);
    }
    asm volatile("" ::: "memory");   // loads may not sink past this

    const uint2 qu  = *(const uint2*)(qkv + (size_t)p * 1024 + c0);
    const uint2 qpu = *(const uint2*)(qkv + (size_t)p * 1024 + 768 + c0);
    const h2 qh01 = ash2(qu.x), qh23 = ash2(qu.y);
    const h2 qph01 = ash2(qpu.x), qph23 = ash2(qpu.y);
    const float q0 = (float)qh01.x, q1 = (float)qh01.y, q2 = (float)qh23.x, q3 = (float)qh23.y;
    const float qp0 = (float)qph01.x, qp1 = (float)qph01.y, qp2 = (float)qph23.x, qp3 = (float)qph23.y;

    const float4 w0 = *(const float4*)&fd1_w[c0];
    const float4 w1 = *(const float4*)&fd1_w[DM_ + c0];
    const float4 w2 = *(const float4*)&fd1_w[2 * DM_ + c0];
    const float4 b1 = *(const float4*)&fd1_b[c0];
    const float4 f2b = *(const float4*)&fd2_b[c0];

    // qb = q . fd2_b (constant over k)
    float qb;
    {
        float tq = q0 * f2b.x + q1 * f2b.y + q2 * f2b.z + q3 * f2b.w;
#pragma unroll
        for (int off = 1; off < 64; off <<= 1) tq += __shfl_xor(tq, off);
        qb = tq;
    }

    // phase 1: logits; h packed to f16 and kept for phase 2
    float lg[16];
    u32 h01r[16], h23r[16];
#pragma unroll
    for (int k = 0; k < 16; ++k) {
        const float d0 = __shfl(dx, k), d1 = __shfl(dy, k), d2 = __shfl(dz, k);
        const float h0 = fmaxf(d0 * w0.x + d1 * w1.x + d2 * w2.x + b1.x, 0.0f);
        const float h1 = fmaxf(d0 * w0.y + d1 * w1.y + d2 * w2.y + b1.y, 0.0f);
        const float h2v = fmaxf(d0 * w0.z + d1 * w1.z + d2 * w2.z + b1.z, 0.0f);
        const float h3 = fmaxf(d0 * w0.w + d1 * w1.w + d2 * w2.w + b1.w, 0.0f);
        h01r[k] = asu32(pkrtz(h0, h1));
        h23r[k] = asu32(pkrtz(h2v, h3));
        const auto k01 = __builtin_amdgcn_cvt_pk_f32_fp8((int)kvr8[k].x, false);
        const auto k23 = __builtin_amdgcn_cvt_pk_f32_fp8((int)kvr8[k].x, true);
        float t = q0 * k01[0] + q1 * k01[1] + q2 * k23[0] + q3 * k23[1]
                + h0 * qp0 + h1 * qp1 + h2v * qp2 + h3 * qp3;
#pragma unroll
        for (int off = 1; off < 64; off <<= 1) t += __shfl_xor(t, off);
        lg[k] = t;
    }

    // softmax over 16 (redundant per lane, all registers)
    float att[16];
    {
        float mx = -3.0e38f;
#pragma unroll
        for (int k = 0; k < 16; ++k) {
            att[k] = (lg[k] + qb) * (1.0f / 16.0f);
            mx = fmaxf(mx, att[k]);
        }
        float s = 0.0f;
#pragma unroll
        for (int k = 0; k < 16; ++k) { att[k] = __expf(att[k] - mx); s += att[k]; }
        const float inv = 1.0f / s;
#pragma unroll
        for (int k = 0; k < 16; ++k) att[k] *= inv;
    }

    // phase 2: pure VALU — rbar = sum att*v (kvr8 regs), hbar = sum att*h (regs)
    float rb[4] = {0, 0, 0, 0}, hb[4] = {0, 0, 0, 0};
#pragma unroll
    for (int k = 0; k < 16; ++k) {
        const auto v01 = __builtin_amdgcn_cvt_pk_f32_fp8((int)kvr8[k].y, false);
        const auto v23 = __builtin_amdgcn_cvt_pk_f32_fp8((int)kvr8[k].y, true);
        const h2 hh01 = ash2(h01r[k]), hh23 = ash2(h23r[k]);
        const float a = att[k];
        rb[0] = fmaf(a, v01[0], rb[0]);
        rb[1] = fmaf(a, v01[1], rb[1]);
        rb[2] = fmaf(a, v23[0], rb[2]);
        rb[3] = fmaf(a, v23[1], rb[3]);
        hb[0] = fmaf(a, (float)hh01.x, hb[0]);
        hb[1] = fmaf(a, (float)hh01.y, hb[1]);
        hb[2] = fmaf(a, (float)hh23.x, hb[2]);
        hb[3] = fmaf(a, (float)hh23.y, hb[3]);
    }

    const uint2 ho = make_uint2(asu32(pkrtz(hb[0], hb[1])), asu32(pkrtz(hb[2], hb[3])));
    const uint2 ro = make_uint2(asu32(pkrtz(rb[0], rb[1])), asu32(pkrtz(rb[2], rb[3])));
    *(uint2*)(ab + (size_t)p * 512 + c0) = ho;
    *(uint2*)(ab + (size_t)p * 512 + 256 + c0) = ro;
}

extern "C" void kernel_launch(void* const* d_in, const int* in_sizes, int n_in,
                              void* d_out, int out_size, void* d_ws, size_t ws_size,
                              hipStream_t stream)
{
    const float* features = (const float*)d_in[0];
    const float* xyz   = (const float*)d_in[1];
    const float* fc1_w = (const float*)d_in[2];
    const float* fc1_b = (const float*)d_in[3];
    const float* fc2_w = (const float*)d_in[4];
    const float* fc2_b = (const float*)d_in[5];
    const float* fd1_w = (const float*)d_in[6];
    const float* fd1_b = (const float*)d_in[7];
    const float* fd2_w = (const float*)d_in[8];
    const float* fd2_b = (const float*)d_in[9];
    const float* wq    = (const float*)d_in[10];
    const float* wk    = (const float*)d_in[11];
    const float* wv    = (const float*)d_in[12];
    float* out = (float*)d_out;

    char* base = (char*)d_ws;
    const size_t MB = 1024 * 1024;
    u32*  part = (u32*)(base + 0);                 // 16 MB (16 segs), dead after mergeA
    f16*  ab   = (f16*)(base + 0);                 // 16 MB [hbar|rbar]
    u32*  m4   = (u32*)(base + 16 * MB);           // 4 MB (4 lists), dead after mergeB
    u8*   kv8  = (u8*)(base + 20 * MB);            // 8 MB fp8 gather buffer
    f16*  qkv  = (f16*)(base + 36 * MB);           // 32 MB
    f16*  featb = (f16*)(base + 68 * MB);          // 4 MB
    int*  idx  = (int*)(base + 72 * MB);           // 1 MB
    char* wb = base + 73 * MB;
    f16* catW  = (f16*)(wb + 0);                   // [1024][256] = 512 KB
    f16* WallT = (f16*)(wb + 512 * 1024);          // [1024][128] = 256 KB
    f16* bt2   = (f16*)(wb + 768 * 1024);          // [128][512]  = 128 KB
    f16* fd2c  = (f16*)(wb + 896 * 1024);
    f16* wqc   = (f16*)(wb + 1024 * 1024);
    f16* fc1c  = (f16*)(wb + 1152 * 1024);
    f16* fc2T  = (f16*)(wb + 1216 * 1024);
    float* b_all = (float*)(wb + 1280 * 1024);
    float* bias2 = (float*)(wb + 1284 * 1024);

    const dim3 blk(256);

    // 1. casts (also seeds bt2 cols [256,512) with fc2^T); k/v rows interleaved in catW
    prep_kernel<<<dim3(8, 8, 8), blk, 0, stream>>>(wq, wk, wv, fd2_w, fc1_w, fc2_w, features,
                                                   catW, fc2T, bt2, fd2c, wqc, fc1c, featb);
    // 2. wqp -> catW rows 768.. (4 tiles) || bt2 cols [0,256) (2 tiles)
    fused_small1_kernel<<<dim3(6), blk, 0, stream>>>(fd2c, wqc, catW + 768 * 256, fc2T, bt2);
    // 3. WallT (8 tiles) || b_all (4) || bias2 (1)
    fused_small2_kernel<<<dim3(13), blk, 0, stream>>>(catW, fc1c, WallT,
                                                      fc1_b, fd2_b, fc2_w, fc2_b, b_all, bias2);
    // 4. qkv GEMM (1024 blocks) || knn_part (1024 blocks) — independent, run concurrently
    fused_main_kernel<<<dim3(2048), blk, 0, stream>>>(featb, WallT, b_all, qkv, xyz, part);
    // 5. kv8 (4096 blocks) || mergeA (256 blocks)
    fused_m4kv8_kernel<<<dim3(4096 + 256), blk, 0, stream>>>(qkv, kv8, part, m4);
    // 6. mergeB -> final knn indices
    knn_mergeB_kernel<<<dim3(NPTS / 256), blk, 0, stream>>>(m4, idx);
    // 7. fused attention -> ab = [hbar | rbar]
    attn_kernel<<<dim3(NPTS / 4), blk, 0, stream>>>(xyz, qkv, kv8, idx,
                                                    fd1_w, fd1_b, fd2_b, ab);
    // 8. out = ab @ bt2^T + bias2 + features, stored TRANSPOSED directly to d_out
    gemm_f16_kernel<<<dim3(1, NPTS / 128), blk, 0, stream>>>(
        ab, bt2, bias2, features, out, nullptr, NPTS, DP_, 512, DP_);

    (void)in_sizes; (void)n_in; (void)out_size; (void)ws_size;
}

// Round 15
// 253.260 us; speedup vs baseline: 1.1969x; 1.1969x over previous
//
#include <hip/hip_runtime.h>
#include <hip/hip_bf16.h>
#include <math.h>

#define B_   4
#define N_   4096
#define K_   16
#define DP_  128
#define DM_  256
#define NPTS (B_ * N_)
#define SEG_ 16
#define CAND_ (N_ / SEG_)   // 256 candidates per segment
#define QPAD 136            // K=128 LDS row stride (f16): 272B, uint4-aligned, low conflict

typedef unsigned int u32;
typedef unsigned char u8;
typedef _Float16 f16;
typedef __attribute__((ext_vector_type(2))) __fp16 h2;     // matches cvt_pkrtz ABI
typedef __attribute__((ext_vector_type(8))) _Float16 f16x8; // MFMA operand
typedef __attribute__((ext_vector_type(4))) float floatx4;

static __device__ __forceinline__ h2 pkrtz(float a, float b) {
    return __builtin_amdgcn_cvt_pkrtz(a, b);
}
static __device__ __forceinline__ u32 asu32(h2 h) { return __builtin_bit_cast(u32, h); }
static __device__ __forceinline__ h2 ash2(u32 u) { return __builtin_bit_cast(h2, u); }

// ---- bitonic primitives on u32 registers ----
#define CEXA(x, y) { u32 _lo = min(x, y); y = max(x, y); x = _lo; }   // x<=y
#define CEXD(x, y) { u32 _hi = max(x, y); y = min(x, y); x = _hi; }   // x>=y

static __device__ __forceinline__ void sort16_desc(u32 c[16]) {
    CEXD(c[0],c[1]);  CEXA(c[2],c[3]);  CEXD(c[4],c[5]);  CEXA(c[6],c[7]);
    CEXD(c[8],c[9]);  CEXA(c[10],c[11]); CEXD(c[12],c[13]); CEXA(c[14],c[15]);

    CEXD(c[0],c[2]);  CEXD(c[1],c[3]);  CEXA(c[4],c[6]);  CEXA(c[5],c[7]);
    CEXD(c[8],c[10]); CEXD(c[9],c[11]); CEXA(c[12],c[14]); CEXA(c[13],c[15]);
    CEXD(c[0],c[1]);  CEXD(c[2],c[3]);  CEXA(c[4],c[5]);  CEXA(c[6],c[7]);
    CEXD(c[8],c[9]);  CEXD(c[10],c[11]); CEXA(c[12],c[13]); CEXA(c[14],c[15]);

    CEXD(c[0],c[4]);  CEXD(c[1],c[5]);  CEXD(c[2],c[6]);  CEXD(c[3],c[7]);
    CEXA(c[8],c[12]); CEXA(c[9],c[13]); CEXA(c[10],c[14]); CEXA(c[11],c[15]);
    CEXD(c[0],c[2]);  CEXD(c[1],c[3]);  CEXD(c[4],c[6]);  CEXD(c[5],c[7]);
    CEXA(c[8],c[10]); CEXA(c[9],c[11]); CEXA(c[12],c[14]); CEXA(c[13],c[15]);
    CEXD(c[0],c[1]);  CEXD(c[2],c[3]);  CEXD(c[4],c[5]);  CEXD(c[6],c[7]);
    CEXA(c[8],c[9]);  CEXA(c[10],c[11]); CEXA(c[12],c[13]); CEXA(c[14],c[15]);

    CEXD(c[0],c[8]);  CEXD(c[1],c[9]);  CEXD(c[2],c[10]); CEXD(c[3],c[11]);
    CEXD(c[4],c[12]); CEXD(c[5],c[13]); CEXD(c[6],c[14]); CEXD(c[7],c[15]);
    CEXD(c[0],c[4]);  CEXD(c[1],c[5]);  CEXD(c[2],c[6]);  CEXD(c[3],c[7]);
    CEXD(c[8],c[12]); CEXD(c[9],c[13]); CEXD(c[10],c[14]); CEXD(c[11],c[15]);
    CEXD(c[0],c[2]);  CEXD(c[1],c[3]);  CEXD(c[4],c[6]);  CEXD(c[5],c[7]);
    CEXD(c[8],c[10]); CEXD(c[9],c[11]); CEXD(c[12],c[14]); CEXD(c[13],c[15]);
    CEXD(c[0],c[1]);  CEXD(c[2],c[3]);  CEXD(c[4],c[5]);  CEXD(c[6],c[7]);
    CEXD(c[8],c[9]);  CEXD(c[10],c[11]); CEXD(c[12],c[13]); CEXD(c[14],c[15]);
}

static __device__ __forceinline__ void remerge16_asc(u32 L[16]) {
    CEXA(L[0],L[8]);  CEXA(L[1],L[9]);  CEXA(L[2],L[10]); CEXA(L[3],L[11]);
    CEXA(L[4],L[12]); CEXA(L[5],L[13]); CEXA(L[6],L[14]); CEXA(L[7],L[15]);
    CEXA(L[0],L[4]);  CEXA(L[1],L[5]);  CEXA(L[2],L[6]);  CEXA(L[3],L[7]);
    CEXA(L[8],L[12]); CEXA(L[9],L[13]); CEXA(L[10],L[14]); CEXA(L[11],L[15]);
    CEXA(L[0],L[2]);  CEXA(L[1],L[3]);  CEXA(L[4],L[6]);  CEXA(L[5],L[7]);
    CEXA(L[8],L[10]); CEXA(L[9],L[11]); CEXA(L[12],L[14]); CEXA(L[13],L[15]);
    CEXA(L[0],L[1]);  CEXA(L[2],L[3]);  CEXA(L[4],L[5]);  CEXA(L[6],L[7]);
    CEXA(L[8],L[9]);  CEXA(L[10],L[11]); CEXA(L[12],L[13]); CEXA(L[14],L[15]);
}

// ---------------- KNN phase 1: bitonic-batch top-16 per (point, segment) ----------------
// Rank key: e = 0.5*|c|^2 - dot(x_n, c)  — rank-equivalent to d2 (monotone shift).
__global__ __launch_bounds__(256, 1) void knn_part_kernel(const float* __restrict__ xyz,
                                                          u32* __restrict__ part)
{
    const int b = blockIdx.z;
    const int s = blockIdx.y;
    const int n = blockIdx.x * 256 + threadIdx.x;
    const float* xb = xyz + (size_t)b * N_ * 3;
    const float xn0 = xb[n * 3 + 0], xn1 = xb[n * 3 + 1], xn2 = xb[n * 3 + 2];

    __shared__ float4 sc[CAND_];
    {
        const int m = s * CAND_ + threadIdx.x;   // CAND_ == 256 == blockDim.x
        const float a0 = xb[m * 3 + 0];
        const float a1 = xb[m * 3 + 1];
        const float a2 = xb[m * 3 + 2];
        sc[threadIdx.x] = make_float4(a0, a1, a2, 0.5f * (a0 * a0 + a1 * a1 + a2 * a2));
    }
    __syncthreads();

    u32 L[16];
#pragma unroll
    for (int i = 0; i < 16; ++i) L[i] = 0xFFFFFFFFu;

    const u32 ibase = (u32)(s * CAND_);
    for (int m0 = 0; m0 < CAND_; m0 += 16) {
        u32 c[16];
#pragma unroll
        for (int t = 0; t < 16; ++t) {
            const float4 cc = sc[m0 + t];
            const float dot = xn0 * cc.x + xn1 * cc.y + xn2 * cc.z;
            const float e = cc.w - dot;
            const int ib = __float_as_int(e);
            const u32 tk = (u32)ib ^ (u32)((ib >> 31) | 0x80000000);
            c[t] = (tk & 0xFFFFF000u) | (ibase + (u32)(m0 + t));
        }
        sort16_desc(c);
#pragma unroll
        for (int i = 0; i < 16; ++i) L[i] = min(L[i], c[i]);
        remerge16_asc(L);
    }

    const int p = b * N_ + n;
#pragma unroll
    for (int j = 0; j < 16; ++j)
        part[(size_t)(s * 16 + j) * NPTS + p] = L[j];
}

// ---------------- generic BK=32 GEMM tile (C[M,N] = A@Bt^T +bias +addC) ----------------
static __device__ void gemm_tile(f16* As, f16* Bs,
    const f16* __restrict__ A, const f16* __restrict__ Bt,
    const float* __restrict__ bias, const float* __restrict__ addC,
    float* __restrict__ CT, f16* __restrict__ Cb,
    int M, int N, int K, int ldc, int bx, int by)
{
    const int tid = threadIdx.x;
    const int m0 = by * 128, n0 = bx * 128;
    const int w = tid >> 6, l = tid & 63;
    const int wm = (w >> 1) * 64, wn = (w & 1) * 64;
    const int fm = l & 15, kq = l >> 4;

    floatx4 acc[4][4];
#pragma unroll
    for (int i = 0; i < 4; ++i)
#pragma unroll
        for (int j = 0; j < 4; ++j)
            acc[i][j] = (floatx4){0.0f, 0.0f, 0.0f, 0.0f};

    for (int k0 = 0; k0 < K; k0 += 32) {
        __syncthreads();
#pragma unroll
        for (int c = 0; c < 2; ++c) {
            const int li = tid + c * 256;
            const int row = li >> 2, part = li & 3;
            *(uint4*)&As[row * 32 + part * 8] =
                *(const uint4*)&A[(size_t)(m0 + row) * K + k0 + part * 8];
            *(uint4*)&Bs[row * 32 + part * 8] =
                *(const uint4*)&Bt[(size_t)(n0 + row) * K + k0 + part * 8];
        }
        __syncthreads();
        f16x8 af[4], bf[4];
#pragma unroll
        for (int i = 0; i < 4; ++i)
            af[i] = *(const f16x8*)&As[(wm + i * 16 + fm) * 32 + kq * 8];
#pragma unroll
        for (int j = 0; j < 4; ++j)
            bf[j] = *(const f16x8*)&Bs[(wn + j * 16 + fm) * 32 + kq * 8];
#pragma unroll
        for (int i = 0; i < 4; ++i)
#pragma unroll
            for (int j = 0; j < 4; ++j)
                acc[i][j] = __builtin_amdgcn_mfma_f32_16x16x32_f16(af[i], bf[j], acc[i][j], 0, 0, 0);
    }

#pragma unroll
    for (int i = 0; i < 4; ++i) {
#pragma unroll
        for (int j = 0; j < 4; ++j) {
            const int col = n0 + wn + j * 16 + fm;
            const int rowb = m0 + wm + i * 16 + kq * 4;
            float4 vv;
#pragma unroll
            for (int r = 0; r < 4; ++r) {
                const int m = rowb + r;
                float v = acc[i][j][r];
                if (bias) v += bias[col];
                if (addC) v += addC[(size_t)m * ldc + col];
                ((float*)&vv)[r] = v;
            }
            if (CT) {   // rows rowb..rowb+3 consecutive n in one batch: transposed store
                const int bb = rowb >> 12;
                *(float4*)&CT[(size_t)(bb * DP_ + col) * N_ + (rowb & (N_ - 1))] = vv;
            } else if (Cb) {
#pragma unroll
                for (int r = 0; r < 4; ++r)
                    Cb[(size_t)(rowb + r) * ldc + col] = (f16)((float*)&vv)[r];
            }
        }
    }
}

__global__ __launch_bounds__(256) void gemm_f16_kernel(
    const f16* __restrict__ A, const f16* __restrict__ Bt,
    const float* __restrict__ bias, const float* __restrict__ addC,
    float* __restrict__ CT, f16* __restrict__ Cb,
    int M, int N, int K, int ldc)
{
    __shared__ __align__(16) f16 As[128 * 32];
    __shared__ __align__(16) f16 Bs[128 * 32];
    gemm_tile(As, Bs, A, Bt, bias, addC, CT, Cb, M, N, K, ldc, blockIdx.x, blockIdx.y);
}

// ---------------- qkv GEMM, K=128 fully resident: ONE barrier, no K-loop staging ----------------
__global__ __launch_bounds__(256) void gemm_qkv_kernel(
    const f16* __restrict__ A,     // featb [NPTS][128]
    const f16* __restrict__ Bt,    // WallT [1024][128]
    const float* __restrict__ bias,
    f16* __restrict__ Cb)          // qkv [NPTS][1024]
{
    __shared__ __align__(16) f16 As[128 * QPAD];
    __shared__ __align__(16) f16 Bs[128 * QPAD];
    const int tid = threadIdx.x;
    const int m0 = blockIdx.y * 128, n0 = blockIdx.x * 128;
    const int w = tid >> 6, l = tid & 63;
    const int wm = (w >> 1) * 64, wn = (w & 1) * 64;
    const int fm = l & 15, kq = l >> 4;

#pragma unroll
    for (int c = 0; c < 8; ++c) {   // 128x128 f16 per matrix = 2048 uint4, 8/thread
        const int li = tid + c * 256;
        const int row = li >> 4, part = li & 15;
        *(uint4*)&As[row * QPAD + part * 8] =
            *(const uint4*)&A[(size_t)(m0 + row) * 128 + part * 8];
        *(uint4*)&Bs[row * QPAD + part * 8] =
            *(const uint4*)&Bt[(size_t)(n0 + row) * 128 + part * 8];
    }
    __syncthreads();

    floatx4 acc[4][4];
#pragma unroll
    for (int i = 0; i < 4; ++i)
#pragma unroll
        for (int j = 0; j < 4; ++j)
            acc[i][j] = (floatx4){0.0f, 0.0f, 0.0f, 0.0f};

#pragma unroll
    for (int kk = 0; kk < 4; ++kk) {
        f16x8 af[4], bf[4];
#pragma unroll
        for (int i = 0; i < 4; ++i)
            af[i] = *(const f16x8*)&As[(wm + i * 16 + fm) * QPAD + kk * 32 + kq * 8];
#pragma unroll
        for (int j = 0; j < 4; ++j)
            bf[j] = *(const f16x8*)&Bs[(wn + j * 16 + fm) * QPAD + kk * 32 + kq * 8];
#pragma unroll
        for (int i = 0; i < 4; ++i)
#pragma unroll
            for (int j = 0; j < 4; ++j)
                acc[i][j] = __builtin_amdgcn_mfma_f32_16x16x32_f16(af[i], bf[j], acc[i][j], 0, 0, 0);
    }

#pragma unroll
    for (int i = 0; i < 4; ++i) {
#pragma unroll
        for (int j = 0; j < 4; ++j) {
            const int col = n0 + wn + j * 16 + fm;
            const int rowb = m0 + wm + i * 16 + kq * 4;
#pragma unroll
            for (int r = 0; r < 4; ++r)
                Cb[(size_t)(rowb + r) * 1024 + col] = (f16)(acc[i][j][r] + bias[col]);
        }
    }
}

// ---------------- kv8 body + single-stage mergeAB body, FUSED ----------------
static __device__ void kv8_body(const f16* __restrict__ qkv, u8* __restrict__ kv8, int id)
{
    const int t = id * 256 + threadIdx.x;   // 0 .. NPTS*64-1
    const int p = t >> 6, g = t & 63;
    const uint4 kv = *(const uint4*)(qkv + (size_t)p * 1024 + 256 + g * 8);
    const h2 k01 = ash2(kv.x), k23 = ash2(kv.y), v01 = ash2(kv.z), v23 = ash2(kv.w);
    int lo = 0, hi = 0;
    lo = __builtin_amdgcn_cvt_pk_fp8_f32((float)k01.x, (float)k01.y, lo, false);
    lo = __builtin_amdgcn_cvt_pk_fp8_f32((float)k23.x, (float)k23.y, lo, true);
    hi = __builtin_amdgcn_cvt_pk_fp8_f32((float)v01.x, (float)v01.y, hi, false);
    hi = __builtin_amdgcn_cvt_pk_fp8_f32((float)v23.x, (float)v23.y, hi, true);
    *(uint2*)(kv8 + (size_t)p * 512 + g * 8) = make_uint2((u32)lo, (u32)hi);
}

static __device__ void mergeAB_body(const u32* __restrict__ part, int* __restrict__ knn_idx,
                                    int id)
{
    const int p = id * 256 + threadIdx.x;   // global point id
    const int b = p >> 12;

    u32 L[16];
#pragma unroll
    for (int i = 0; i < 16; ++i) L[i] = 0xFFFFFFFFu;

    for (int s = 0; s < SEG_; ++s) {
        u32 seg[16];
#pragma unroll
        for (int j = 0; j < 16; ++j)
            seg[j] = part[(size_t)(s * 16 + j) * NPTS + p];
#pragma unroll
        for (int i = 0; i < 16; ++i) L[i] = min(L[i], seg[15 - i]);
        remerge16_asc(L);
    }

    int* o = knn_idx + (size_t)p * K_;
#pragma unroll
    for (int i = 0; i < 16; ++i) o[i] = b * N_ + (int)(L[i] & 0xFFFu);
}

// matched footprints (both VGPR<50, no LDS) — r14's fused_main failed on mismatch
__global__ __launch_bounds__(256) void fused_kv8merge_kernel(
    const f16* __restrict__ qkv, u8* __restrict__ kv8,
    const u32* __restrict__ part, int* __restrict__ knn_idx)
{
    const int id = blockIdx.x;
    if (id < NPTS * 64 / 256) kv8_body(qkv, kv8, id);
    else                      mergeAB_body(part, knn_idx, id - NPTS * 64 / 256);
}

// ---------------- one-shot prep: weight transpose-casts + straight casts (f16) ----------------
// k/v rows of catW INTERLEAVED: k-col c -> row 256+8*(c/4)+(c%4); v-col c -> +4.
__global__ __launch_bounds__(256) void prep_kernel(
    const float* __restrict__ wq, const float* __restrict__ wk, const float* __restrict__ wv,
    const float* __restrict__ fd2, const float* __restrict__ fc1, const float* __restrict__ fc2,
    const float* __restrict__ feat,
    f16* __restrict__ catW, f16* __restrict__ fc2T, f16* __restrict__ bt2,
    f16* __restrict__ fd2c, f16* __restrict__ wqc, f16* __restrict__ fc1c,
    f16* __restrict__ featb)
{
    __shared__ float t[32][33];
    const int job = blockIdx.z;
    const int tid = threadIdx.x;

    if (job < 4) {
        const float* in; int R, C;
        switch (job) {
            case 0: in = wq;  R = DM_; C = DM_; break;
            case 1: in = wk;  R = DM_; C = DM_; break;
            case 2: in = wv;  R = DM_; C = DM_; break;
            default: in = fc2; R = DM_; C = DP_; break;
        }
        const int c0 = blockIdx.x * 32, r0 = blockIdx.y * 32;
        if (c0 >= C || r0 >= R) return;
        const int lx = tid & 31, ly = tid >> 5;
#pragma unroll
        for (int i = 0; i < 32; i += 8)
            t[ly + i][lx] = in[(size_t)(r0 + ly + i) * C + c0 + lx];
        __syncthreads();
#pragma unroll
        for (int i = 0; i < 32; i += 8) {
            const int c = c0 + ly + i;
            const f16 v = (f16)t[lx][ly + i];
            int n;
            switch (job) {
                case 0: n = c; break;
                case 1: n = 256 + ((c >> 2) << 3) + (c & 3); break;
                case 2: n = 256 + ((c >> 2) << 3) + 4 + (c & 3); break;
                default: n = -1; break;
            }
            if (job < 3) {
                catW[(size_t)n * DM_ + r0 + lx] = v;
            } else {
                fc2T[(size_t)c * DM_ + r0 + lx] = v;
                bt2[(size_t)c * 512 + 256 + r0 + lx] = v;
            }
        }
    } else {
        const int bid = blockIdx.y * 8 + blockIdx.x;
        const int tId = bid * 256 + tid;
        const float* in; f16* outp; int n4;
        if (job == 4)      { in = fd2;  outp = fd2c;  n4 = (DM_ * DM_) / 4; }
        else if (job == 5) { in = wq;   outp = wqc;   n4 = (DM_ * DM_) / 4; }
        else if (job == 6) { in = fc1;  outp = fc1c;  n4 = (DP_ * DM_) / 4; }
        else               { in = feat; outp = featb; n4 = (NPTS * DP_) / 4; }
        for (int i = tId; i < n4; i += 16384) {
            const float4 v = ((const float4*)in)[i];
            const u32 lo = asu32(pkrtz(v.x, v.y));
            const u32 hi = asu32(pkrtz(v.z, v.w));
            ((uint2*)outp)[i] = make_uint2(lo, hi);
        }
    }
}

// ---------------- fused small GEMMs 1: wqp (4 tiles) + bt2 (2 tiles) ----------------
__global__ __launch_bounds__(256) void fused_small1_kernel(
    const f16* __restrict__ fd2c, const f16* __restrict__ wqc,
    f16* __restrict__ catWqp,                   // catW + 768*256
    const f16* __restrict__ fc2T, f16* __restrict__ bt2)
{
    __shared__ __align__(16) f16 As[128 * 32];
    __shared__ __align__(16) f16 Bs[128 * 32];
    const int id = blockIdx.x;
    if (id < 4)
        gemm_tile(As, Bs, fd2c, wqc, nullptr, nullptr, nullptr, catWqp,
                  DM_, DM_, DM_, DM_, id & 1, id >> 1);
    else
        gemm_tile(As, Bs, fc2T, fd2c, nullptr, nullptr, nullptr, bt2,
                  DP_, DM_, DM_, 512, id - 4, 0);
}

// ---------------- fused small GEMMs 2: WallT (8 tiles) + folded biases (5 blocks) ----------------
__global__ __launch_bounds__(256) void fused_small2_kernel(
    const f16* __restrict__ catW, const f16* __restrict__ fc1c, f16* __restrict__ WallT,
    const float* __restrict__ fc1_b, const float* __restrict__ fd2_b,
    const float* __restrict__ fc2_w, const float* __restrict__ fc2_b,
    float* __restrict__ b_all, float* __restrict__ bias2)
{
    __shared__ __align__(16) f16 As[128 * 32];
    __shared__ __align__(16) f16 Bs[128 * 32];
    const int id = blockIdx.x;
    const int tid = threadIdx.x;
    if (id < 8) {
        gemm_tile(As, Bs, catW, fc1c, nullptr, nullptr, nullptr, WallT,
                  1024, DP_, DM_, DP_, 0, id);
    } else if (id < 12) {
        const int n = (id - 8) * 256 + tid;
        float s = 0.0f;
        for (int j = 0; j < DM_; ++j)
            s += fc1_b[j] * (float)catW[(size_t)n * DM_ + j];
        b_all[n] = s;
    } else if (tid < DP_) {
        float s = fc2_b[tid];
        for (int t = 0; t < DM_; ++t)
            s += fd2_b[t] * fc2_w[(size_t)t * DP_ + tid];
        bias2[tid] = s;
    }
}

// ---------------- fused attention: one WAVE per point; fp8 kv gather (8 B/lane/neighbor) ----
__global__ __launch_bounds__(256, 1) void attn_kernel(
    const float* __restrict__ xyz, const f16* __restrict__ qkv,
    const u8* __restrict__ kv8, const int* __restrict__ knn_idx,
    const float* __restrict__ fd1_w, const float* __restrict__ fd1_b,
    const float* __restrict__ fd2_b,
    f16* __restrict__ ab)
{
    const int wave = threadIdx.x >> 6, l = threadIdx.x & 63;
    const int p = blockIdx.x * 4 + wave;
    const int c0 = l * 4;

    int gi = 0; float dx = 0.0f, dy = 0.0f, dz = 0.0f;
    if (l < 16) {
        gi = knn_idx[p * K_ + l];
        dx = xyz[(size_t)p * 3 + 0] - xyz[(size_t)gi * 3 + 0];
        dy = xyz[(size_t)p * 3 + 1] - xyz[(size_t)gi * 3 + 1];
        dz = xyz[(size_t)p * 3 + 2] - xyz[(size_t)gi * 3 + 2];
    }

    // prefetch ALL 16 neighbor kv8 rows (independent 8B loads), pin above compute
    uint2 kvr8[16];
#pragma unroll
    for (int k = 0; k < 16; ++k) {
        const int gik = __shfl(gi, k);
        kvr8[k] = *(const uint2*)(kv8 + (size_t)gik * 512 + l * 8);
    }
    asm volatile("" ::: "memory");   // loads may not sink past this

    const uint2 qu  = *(const uint2*)(qkv + (size_t)p * 1024 + c0);
    const uint2 qpu = *(const uint2*)(qkv + (size_t)p * 1024 + 768 + c0);
    const h2 qh01 = ash2(qu.x), qh23 = ash2(qu.y);
    const h2 qph01 = ash2(qpu.x), qph23 = ash2(qpu.y);
    const float q0 = (float)qh01.x, q1 = (float)qh01.y, q2 = (float)qh23.x, q3 = (float)qh23.y;
    const float qp0 = (float)qph01.x, qp1 = (float)qph01.y, qp2 = (float)qph23.x, qp3 = (float)qph23.y;

    const float4 w0 = *(const float4*)&fd1_w[c0];
    const float4 w1 = *(const float4*)&fd1_w[DM_ + c0];
    const float4 w2 = *(const float4*)&fd1_w[2 * DM_ + c0];
    const float4 b1 = *(const float4*)&fd1_b[c0];
    const float4 f2b = *(const float4*)&fd2_b[c0];

    // qb = q . fd2_b (constant over k)
    float qb;
    {
        float tq = q0 * f2b.x + q1 * f2b.y + q2 * f2b.z + q3 * f2b.w;
#pragma unroll
        for (int off = 1; off < 64; off <<= 1) tq += __shfl_xor(tq, off);
        qb = tq;
    }

    // phase 1: logits; h packed to f16 and kept for phase 2
    float lg[16];
    u32 h01r[16], h23r[16];
#pragma unroll
    for (int k = 0; k < 16; ++k) {
        const float d0 = __shfl(dx, k), d1 = __shfl(dy, k), d2 = __shfl(dz, k);
        const float h0 = fmaxf(d0 * w0.x + d1 * w1.x + d2 * w2.x + b1.x, 0.0f);
        const float h1 = fmaxf(d0 * w0.y + d1 * w1.y + d2 * w2.y + b1.y, 0.0f);
        const float h2v = fmaxf(d0 * w0.z + d1 * w1.z + d2 * w2.z + b1.z, 0.0f);
        const float h3 = fmaxf(d0 * w0.w + d1 * w1.w + d2 * w2.w + b1.w, 0.0f);
        h01r[k] = asu32(pkrtz(h0, h1));
        h23r[k] = asu32(pkrtz(h2v, h3));
        const auto k01 = __builtin_amdgcn_cvt_pk_f32_fp8((int)kvr8[k].x, false);
        const auto k23 = __builtin_amdgcn_cvt_pk_f32_fp8((int)kvr8[k].x, true);
        float t = q0 * k01[0] + q1 * k01[1] + q2 * k23[0] + q3 * k23[1]
                + h0 * qp0 + h1 * qp1 + h2v * qp2 + h3 * qp3;
#pragma unroll
        for (int off = 1; off < 64; off <<= 1) t += __shfl_xor(t, off);
        lg[k] = t;
    }

    // softmax over 16 (redundant per lane, all registers)
    float att[16];
    {
        float mx = -3.0e38f;
#pragma unroll
        for (int k = 0; k < 16; ++k) {
            att[k] = (lg[k] + qb) * (1.0f / 16.0f);
            mx = fmaxf(mx, att[k]);
        }
        float s = 0.0f;
#pragma unroll
        for (int k = 0; k < 16; ++k) { att[k] = __expf(att[k] - mx); s += att[k]; }
        const float inv = 1.0f / s;
#pragma unroll
        for (int k = 0; k < 16; ++k) att[k] *= inv;
    }

    // phase 2: pure VALU — rbar = sum att*v (kvr8 regs), hbar = sum att*h (regs)
    float rb[4] = {0, 0, 0, 0}, hb[4] = {0, 0, 0, 0};
#pragma unroll
    for (int k = 0; k < 16; ++k) {
        const auto v01 = __builtin_amdgcn_cvt_pk_f32_fp8((int)kvr8[k].y, false);
        const auto v23 = __builtin_amdgcn_cvt_pk_f32_fp8((int)kvr8[k].y, true);
        const h2 hh01 = ash2(h01r[k]), hh23 = ash2(h23r[k]);
        const float a = att[k];
        rb[0] = fmaf(a, v01[0], rb[0]);
        rb[1] = fmaf(a, v01[1], rb[1]);
        rb[2] = fmaf(a, v23[0], rb[2]);
        rb[3] = fmaf(a, v23[1], rb[3]);
        hb[0] = fmaf(a, (float)hh01.x, hb[0]);
        hb[1] = fmaf(a, (float)hh01.y, hb[1]);
        hb[2] = fmaf(a, (float)hh23.x, hb[2]);
        hb[3] = fmaf(a, (float)hh23.y, hb[3]);
    }

    const uint2 ho = make_uint2(asu32(pkrtz(hb[0], hb[1])), asu32(pkrtz(hb[2], hb[3])));
    const uint2 ro = make_uint2(asu32(pkrtz(rb[0], rb[1])), asu32(pkrtz(rb[2], rb[3])));
    *(uint2*)(ab + (size_t)p * 512 + c0) = ho;
    *(uint2*)(ab + (size_t)p * 512 + 256 + c0) = ro;
}

extern "C" void kernel_launch(void* const* d_in, const int* in_sizes, int n_in,
                              void* d_out, int out_size, void* d_ws, size_t ws_size,
                              hipStream_t stream)
{
    const float* features = (const float*)d_in[0];
    const float* xyz   = (const float*)d_in[1];
    const float* fc1_w = (const float*)d_in[2];
    const float* fc1_b = (const float*)d_in[3];
    const float* fc2_w = (const float*)d_in[4];
    const float* fc2_b = (const float*)d_in[5];
    const float* fd1_w = (const float*)d_in[6];
    const float* fd1_b = (const float*)d_in[7];
    const float* fd2_w = (const float*)d_in[8];
    const float* fd2_b = (const float*)d_in[9];
    const float* wq    = (const float*)d_in[10];
    const float* wk    = (const float*)d_in[11];
    const float* wv    = (const float*)d_in[12];
    float* out = (float*)d_out;

    char* base = (char*)d_ws;
    const size_t MB = 1024 * 1024;
    u32*  part = (u32*)(base + 0);                 // 16 MB (16 segs), dead after merge
    f16*  ab   = (f16*)(base + 0);                 // 16 MB [hbar|rbar]
    u8*   kv8  = (u8*)(base + 20 * MB);            // 8 MB fp8 gather buffer
    f16*  qkv  = (f16*)(base + 36 * MB);           // 32 MB
    f16*  featb = (f16*)(base + 68 * MB);          // 4 MB
    int*  idx  = (int*)(base + 72 * MB);           // 1 MB
    char* wb = base + 73 * MB;
    f16* catW  = (f16*)(wb + 0);                   // [1024][256] = 512 KB
    f16* WallT = (f16*)(wb + 512 * 1024);          // [1024][128] = 256 KB
    f16* bt2   = (f16*)(wb + 768 * 1024);          // [128][512]  = 128 KB
    f16* fd2c  = (f16*)(wb + 896 * 1024);
    f16* wqc   = (f16*)(wb + 1024 * 1024);
    f16* fc1c  = (f16*)(wb + 1152 * 1024);
    f16* fc2T  = (f16*)(wb + 1216 * 1024);
    float* b_all = (float*)(wb + 1280 * 1024);
    float* bias2 = (float*)(wb + 1284 * 1024);

    const dim3 blk(256);

    // 1. casts (also seeds bt2 cols [256,512) with fc2^T); k/v rows interleaved in catW
    prep_kernel<<<dim3(8, 8, 8), blk, 0, stream>>>(wq, wk, wv, fd2_w, fc1_w, fc2_w, features,
                                                   catW, fc2T, bt2, fd2c, wqc, fc1c, featb);
    // 2. wqp -> catW rows 768.. (4 tiles) || bt2 cols [0,256) (2 tiles)
    fused_small1_kernel<<<dim3(6), blk, 0, stream>>>(fd2c, wqc, catW + 768 * 256, fc2T, bt2);
    // 3. WallT (8 tiles) || b_all (4) || bias2 (1)
    fused_small2_kernel<<<dim3(13), blk, 0, stream>>>(catW, fc1c, WallT,
                                                      fc1_b, fd2_b, fc2_w, fc2_b, b_all, bias2);
    // 4. KNN partial top-16 (separate dispatch — r14 fusion coupled resources, -40%)
    knn_part_kernel<<<dim3(N_ / 256, SEG_, B_), blk, 0, stream>>>(xyz, part);
    // 5. [q | kv-interleaved | qp] = features @ WallT^T + b_all  (K=128, single-barrier)
    gemm_qkv_kernel<<<dim3(1024 / 128, NPTS / 128), blk, 0, stream>>>(featb, WallT, b_all, qkv);
    // 6. kv8 fp8 buffer (4096 blocks) || single-stage 16-segment merge (64 blocks)
    fused_kv8merge_kernel<<<dim3(NPTS * 64 / 256 + NPTS / 256), blk, 0, stream>>>(
        qkv, kv8, part, idx);
    // 7. fused attention -> ab = [hbar | rbar]
    attn_kernel<<<dim3(NPTS / 4), blk, 0, stream>>>(xyz, qkv, kv8, idx,
                                                    fd1_w, fd1_b, fd2_b, ab);
    // 8. out = ab @ bt2^T + bias2 + features, stored TRANSPOSED directly to d_out
    gemm_f16_kernel<<<dim3(1, NPTS / 128), blk, 0, stream>>>(
        ab, bt2, bias2, features, out, nullptr, NPTS, DP_, 512, DP_);

    (void)in_sizes; (void)n_in; (void)out_size; (void)ws_size;
}

// Round 16
// 252.698 us; speedup vs baseline: 1.1996x; 1.0022x over previous
//
#include <hip/hip_runtime.h>
#include <hip/hip_bf16.h>
#include <math.h>

#define B_   4
#define N_   4096
#define K_   16
#define DP_  128
#define DM_  256
#define NPTS (B_ * N_)
#define SEG_ 16
#define CAND_ (N_ / SEG_)   // 256 candidates per segment
#define QPAD 136            // K=128 LDS row stride (f16): 272B, uint4-aligned, low conflict

typedef unsigned int u32;
typedef unsigned char u8;
typedef _Float16 f16;
typedef __attribute__((ext_vector_type(2))) __fp16 h2;     // matches cvt_pkrtz ABI
typedef __attribute__((ext_vector_type(8))) _Float16 f16x8; // MFMA operand
typedef __attribute__((ext_vector_type(4))) float floatx4;

static __device__ __forceinline__ h2 pkrtz(float a, float b) {
    return __builtin_amdgcn_cvt_pkrtz(a, b);
}
static __device__ __forceinline__ u32 asu32(h2 h) { return __builtin_bit_cast(u32, h); }
static __device__ __forceinline__ h2 ash2(u32 u) { return __builtin_bit_cast(h2, u); }

// ---- bitonic primitives on u32 registers ----
#define CEXA(x, y) { u32 _lo = min(x, y); y = max(x, y); x = _lo; }   // x<=y
#define CEXD(x, y) { u32 _hi = max(x, y); y = min(x, y); x = _hi; }   // x>=y

static __device__ __forceinline__ void sort16_desc(u32 c[16]) {
    CEXD(c[0],c[1]);  CEXA(c[2],c[3]);  CEXD(c[4],c[5]);  CEXA(c[6],c[7]);
    CEXD(c[8],c[9]);  CEXA(c[10],c[11]); CEXD(c[12],c[13]); CEXA(c[14],c[15]);

    CEXD(c[0],c[2]);  CEXD(c[1],c[3]);  CEXA(c[4],c[6]);  CEXA(c[5],c[7]);
    CEXD(c[8],c[10]); CEXD(c[9],c[11]); CEXA(c[12],c[14]); CEXA(c[13],c[15]);
    CEXD(c[0],c[1]);  CEXD(c[2],c[3]);  CEXA(c[4],c[5]);  CEXA(c[6],c[7]);
    CEXD(c[8],c[9]);  CEXD(c[10],c[11]); CEXA(c[12],c[13]); CEXA(c[14],c[15]);

    CEXD(c[0],c[4]);  CEXD(c[1],c[5]);  CEXD(c[2],c[6]);  CEXD(c[3],c[7]);
    CEXA(c[8],c[12]); CEXA(c[9],c[13]); CEXA(c[10],c[14]); CEXA(c[11],c[15]);
    CEXD(c[0],c[2]);  CEXD(c[1],c[3]);  CEXD(c[4],c[6]);  CEXD(c[5],c[7]);
    CEXA(c[8],c[10]); CEXA(c[9],c[11]); CEXA(c[12],c[14]); CEXA(c[13],c[15]);
    CEXD(c[0],c[1]);  CEXD(c[2],c[3]);  CEXD(c[4],c[5]);  CEXD(c[6],c[7]);
    CEXA(c[8],c[9]);  CEXA(c[10],c[11]); CEXA(c[12],c[13]); CEXA(c[14],c[15]);

    CEXD(c[0],c[8]);  CEXD(c[1],c[9]);  CEXD(c[2],c[10]); CEXD(c[3],c[11]);
    CEXD(c[4],c[12]); CEXD(c[5],c[13]); CEXD(c[6],c[14]); CEXD(c[7],c[15]);
    CEXD(c[0],c[4]);  CEXD(c[1],c[5]);  CEXD(c[2],c[6]);  CEXD(c[3],c[7]);
    CEXD(c[8],c[12]); CEXD(c[9],c[13]); CEXD(c[10],c[14]); CEXD(c[11],c[15]);
    CEXD(c[0],c[2]);  CEXD(c[1],c[3]);  CEXD(c[4],c[6]);  CEXD(c[5],c[7]);
    CEXD(c[8],c[10]); CEXD(c[9],c[11]); CEXD(c[12],c[14]); CEXD(c[13],c[15]);
    CEXD(c[0],c[1]);  CEXD(c[2],c[3]);  CEXD(c[4],c[5]);  CEXD(c[6],c[7]);
    CEXD(c[8],c[9]);  CEXD(c[10],c[11]); CEXD(c[12],c[13]); CEXD(c[14],c[15]);
}

static __device__ __forceinline__ void remerge16_asc(u32 L[16]) {
    CEXA(L[0],L[8]);  CEXA(L[1],L[9]);  CEXA(L[2],L[10]); CEXA(L[3],L[11]);
    CEXA(L[4],L[12]); CEXA(L[5],L[13]); CEXA(L[6],L[14]); CEXA(L[7],L[15]);
    CEXA(L[0],L[4]);  CEXA(L[1],L[5]);  CEXA(L[2],L[6]);  CEXA(L[3],L[7]);
    CEXA(L[8],L[12]); CEXA(L[9],L[13]); CEXA(L[10],L[14]); CEXA(L[11],L[15]);
    CEXA(L[0],L[2]);  CEXA(L[1],L[3]);  CEXA(L[4],L[6]);  CEXA(L[5],L[7]);
    CEXA(L[8],L[10]); CEXA(L[9],L[11]); CEXA(L[12],L[14]); CEXA(L[13],L[15]);
    CEXA(L[0],L[1]);  CEXA(L[2],L[3]);  CEXA(L[4],L[5]);  CEXA(L[6],L[7]);
    CEXA(L[8],L[9]);  CEXA(L[10],L[11]); CEXA(L[12],L[13]); CEXA(L[14],L[15]);
}

// ---------------- KNN phase 1: bitonic-batch top-16 per (point, segment) ----------------
// Rank key: e = 0.5*|c|^2 - dot(x_n, c) — rank-equivalent to d2. Computed as pure
// 3-FMA chain with pre-negated query; mask kept in a variable (SGPR) so the
// (tk & mask) | idx can fuse to v_and_or_b32.
__global__ __launch_bounds__(256, 1) void knn_part_kernel(const float* __restrict__ xyz,
                                                          u32* __restrict__ part)
{
    const int b = blockIdx.z;
    const int s = blockIdx.y;
    const int n = blockIdx.x * 256 + threadIdx.x;
    const float* xb = xyz + (size_t)b * N_ * 3;
    const float nx0 = -xb[n * 3 + 0], nx1 = -xb[n * 3 + 1], nx2 = -xb[n * 3 + 2];
    const u32 kmask = 0xFFFFF000u;

    __shared__ float4 sc[CAND_];
    {
        const int m = s * CAND_ + threadIdx.x;   // CAND_ == 256 == blockDim.x
        const float a0 = xb[m * 3 + 0];
        const float a1 = xb[m * 3 + 1];
        const float a2 = xb[m * 3 + 2];
        sc[threadIdx.x] = make_float4(a0, a1, a2, 0.5f * (a0 * a0 + a1 * a1 + a2 * a2));
    }
    __syncthreads();

    u32 L[16];
#pragma unroll
    for (int i = 0; i < 16; ++i) L[i] = 0xFFFFFFFFu;

    const u32 ibase = (u32)(s * CAND_);
    for (int m0 = 0; m0 < CAND_; m0 += 16) {
        u32 c[16];
#pragma unroll
        for (int t = 0; t < 16; ++t) {
            const float4 cc = sc[m0 + t];
            const float e = fmaf(nx0, cc.x, fmaf(nx1, cc.y, fmaf(nx2, cc.z, cc.w)));
            const int ib = __float_as_int(e);
            const u32 tk = (u32)ib ^ (u32)((ib >> 31) | 0x80000000);
            c[t] = (tk & kmask) | (ibase + (u32)(m0 + t));
        }
        sort16_desc(c);
#pragma unroll
        for (int i = 0; i < 16; ++i) L[i] = min(L[i], c[i]);
        remerge16_asc(L);
    }

    const int p = b * N_ + n;
#pragma unroll
    for (int j = 0; j < 16; ++j)
        part[(size_t)(s * 16 + j) * NPTS + p] = L[j];
}

// ---------------- generic BK=32 GEMM tile (C[M,N] = A@Bt^T +bias +addC) ----------------
static __device__ void gemm_tile(f16* As, f16* Bs,
    const f16* __restrict__ A, const f16* __restrict__ Bt,
    const float* __restrict__ bias, const float* __restrict__ addC,
    float* __restrict__ CT, f16* __restrict__ Cb,
    int M, int N, int K, int ldc, int bx, int by)
{
    const int tid = threadIdx.x;
    const int m0 = by * 128, n0 = bx * 128;
    const int w = tid >> 6, l = tid & 63;
    const int wm = (w >> 1) * 64, wn = (w & 1) * 64;
    const int fm = l & 15, kq = l >> 4;

    floatx4 acc[4][4];
#pragma unroll
    for (int i = 0; i < 4; ++i)
#pragma unroll
        for (int j = 0; j < 4; ++j)
            acc[i][j] = (floatx4){0.0f, 0.0f, 0.0f, 0.0f};

    for (int k0 = 0; k0 < K; k0 += 32) {
        __syncthreads();
#pragma unroll
        for (int c = 0; c < 2; ++c) {
            const int li = tid + c * 256;
            const int row = li >> 2, part = li & 3;
            *(uint4*)&As[row * 32 + part * 8] =
                *(const uint4*)&A[(size_t)(m0 + row) * K + k0 + part * 8];
            *(uint4*)&Bs[row * 32 + part * 8] =
                *(const uint4*)&Bt[(size_t)(n0 + row) * K + k0 + part * 8];
        }
        __syncthreads();
        f16x8 af[4], bf[4];
#pragma unroll
        for (int i = 0; i < 4; ++i)
            af[i] = *(const f16x8*)&As[(wm + i * 16 + fm) * 32 + kq * 8];
#pragma unroll
        for (int j = 0; j < 4; ++j)
            bf[j] = *(const f16x8*)&Bs[(wn + j * 16 + fm) * 32 + kq * 8];
#pragma unroll
        for (int i = 0; i < 4; ++i)
#pragma unroll
            for (int j = 0; j < 4; ++j)
                acc[i][j] = __builtin_amdgcn_mfma_f32_16x16x32_f16(af[i], bf[j], acc[i][j], 0, 0, 0);
    }

#pragma unroll
    for (int i = 0; i < 4; ++i) {
#pragma unroll
        for (int j = 0; j < 4; ++j) {
            const int col = n0 + wn + j * 16 + fm;
            const int rowb = m0 + wm + i * 16 + kq * 4;
            float4 vv;
#pragma unroll
            for (int r = 0; r < 4; ++r) {
                const int m = rowb + r;
                float v = acc[i][j][r];
                if (bias) v += bias[col];
                if (addC) v += addC[(size_t)m * ldc + col];
                ((float*)&vv)[r] = v;
            }
            if (CT) {   // rows rowb..rowb+3 consecutive n in one batch: transposed store
                const int bb = rowb >> 12;
                *(float4*)&CT[(size_t)(bb * DP_ + col) * N_ + (rowb & (N_ - 1))] = vv;
            } else if (Cb) {
#pragma unroll
                for (int r = 0; r < 4; ++r)
                    Cb[(size_t)(rowb + r) * ldc + col] = (f16)((float*)&vv)[r];
            }
        }
    }
}

__global__ __launch_bounds__(256) void gemm_f16_kernel(
    const f16* __restrict__ A, const f16* __restrict__ Bt,
    const float* __restrict__ bias, const float* __restrict__ addC,
    float* __restrict__ CT, f16* __restrict__ Cb,
    int M, int N, int K, int ldc)
{
    __shared__ __align__(16) f16 As[128 * 32];
    __shared__ __align__(16) f16 Bs[128 * 32];
    gemm_tile(As, Bs, A, Bt, bias, addC, CT, Cb, M, N, K, ldc, blockIdx.x, blockIdx.y);
}

// ---------------- qkv GEMM, K=128 fully resident: ONE barrier, no K-loop staging ----------------
__global__ __launch_bounds__(256) void gemm_qkv_kernel(
    const f16* __restrict__ A,     // featb [NPTS][128]
    const f16* __restrict__ Bt,    // WallT [1024][128]
    const float* __restrict__ bias,
    f16* __restrict__ Cb)          // qkv [NPTS][1024]
{
    __shared__ __align__(16) f16 As[128 * QPAD];
    __shared__ __align__(16) f16 Bs[128 * QPAD];
    const int tid = threadIdx.x;
    const int m0 = blockIdx.y * 128, n0 = blockIdx.x * 128;
    const int w = tid >> 6, l = tid & 63;
    const int wm = (w >> 1) * 64, wn = (w & 1) * 64;
    const int fm = l & 15, kq = l >> 4;

#pragma unroll
    for (int c = 0; c < 8; ++c) {   // 128x128 f16 per matrix = 2048 uint4, 8/thread
        const int li = tid + c * 256;
        const int row = li >> 4, part = li & 15;
        *(uint4*)&As[row * QPAD + part * 8] =
            *(const uint4*)&A[(size_t)(m0 + row) * 128 + part * 8];
        *(uint4*)&Bs[row * QPAD + part * 8] =
            *(const uint4*)&Bt[(size_t)(n0 + row) * 128 + part * 8];
    }
    __syncthreads();

    floatx4 acc[4][4];
#pragma unroll
    for (int i = 0; i < 4; ++i)
#pragma unroll
        for (int j = 0; j < 4; ++j)
            acc[i][j] = (floatx4){0.0f, 0.0f, 0.0f, 0.0f};

#pragma unroll
    for (int kk = 0; kk < 4; ++kk) {
        f16x8 af[4], bf[4];
#pragma unroll
        for (int i = 0; i < 4; ++i)
            af[i] = *(const f16x8*)&As[(wm + i * 16 + fm) * QPAD + kk * 32 + kq * 8];
#pragma unroll
        for (int j = 0; j < 4; ++j)
            bf[j] = *(const f16x8*)&Bs[(wn + j * 16 + fm) * QPAD + kk * 32 + kq * 8];
#pragma unroll
        for (int i = 0; i < 4; ++i)
#pragma unroll
            for (int j = 0; j < 4; ++j)
                acc[i][j] = __builtin_amdgcn_mfma_f32_16x16x32_f16(af[i], bf[j], acc[i][j], 0, 0, 0);
    }

#pragma unroll
    for (int i = 0; i < 4; ++i) {
#pragma unroll
        for (int j = 0; j < 4; ++j) {
            const int col = n0 + wn + j * 16 + fm;
            const int rowb = m0 + wm + i * 16 + kq * 4;
#pragma unroll
            for (int r = 0; r < 4; ++r)
                Cb[(size_t)(rowb + r) * 1024 + col] = (f16)(acc[i][j][r] + bias[col]);
        }
    }
}

// ---------------- kv8 body + single-stage mergeAB body, FUSED ----------------
static __device__ void kv8_body(const f16* __restrict__ qkv, u8* __restrict__ kv8, int id)
{
    const int t = id * 256 + threadIdx.x;   // 0 .. NPTS*64-1
    const int p = t >> 6, g = t & 63;
    const uint4 kv = *(const uint4*)(qkv + (size_t)p * 1024 + 256 + g * 8);
    const h2 k01 = ash2(kv.x), k23 = ash2(kv.y), v01 = ash2(kv.z), v23 = ash2(kv.w);
    int lo = 0, hi = 0;
    lo = __builtin_amdgcn_cvt_pk_fp8_f32((float)k01.x, (float)k01.y, lo, false);
    lo = __builtin_amdgcn_cvt_pk_fp8_f32((float)k23.x, (float)k23.y, lo, true);
    hi = __builtin_amdgcn_cvt_pk_fp8_f32((float)v01.x, (float)v01.y, hi, false);
    hi = __builtin_amdgcn_cvt_pk_fp8_f32((float)v23.x, (float)v23.y, hi, true);
    *(uint2*)(kv8 + (size_t)p * 512 + g * 8) = make_uint2((u32)lo, (u32)hi);
}

static __device__ void mergeAB_body(const u32* __restrict__ part, int* __restrict__ knn_idx,
                                    int id)
{
    const int p = id * 256 + threadIdx.x;   // global point id
    const int b = p >> 12;

    u32 L[16];
#pragma unroll
    for (int i = 0; i < 16; ++i) L[i] = 0xFFFFFFFFu;

    for (int s = 0; s < SEG_; ++s) {
        u32 seg[16];
#pragma unroll
        for (int j = 0; j < 16; ++j)
            seg[j] = part[(size_t)(s * 16 + j) * NPTS + p];
#pragma unroll
        for (int i = 0; i < 16; ++i) L[i] = min(L[i], seg[15 - i]);
        remerge16_asc(L);
    }

    int* o = knn_idx + (size_t)p * K_;
#pragma unroll
    for (int i = 0; i < 16; ++i) o[i] = b * N_ + (int)(L[i] & 0xFFFu);
}

// matched footprints (both VGPR<50, no LDS)
__global__ __launch_bounds__(256) void fused_kv8merge_kernel(
    const f16* __restrict__ qkv, u8* __restrict__ kv8,
    const u32* __restrict__ part, int* __restrict__ knn_idx)
{
    const int id = blockIdx.x;
    if (id < NPTS * 64 / 256) kv8_body(qkv, kv8, id);
    else                      mergeAB_body(part, knn_idx, id - NPTS * 64 / 256);
}

// ---------------- one-shot prep: weight transpose-casts + straight casts (f16) ----------------
// k/v rows of catW INTERLEAVED: k-col c -> row 256+8*(c/4)+(c%4); v-col c -> +4.
__global__ __launch_bounds__(256) void prep_kernel(
    const float* __restrict__ wq, const float* __restrict__ wk, const float* __restrict__ wv,
    const float* __restrict__ fd2, const float* __restrict__ fc1, const float* __restrict__ fc2,
    const float* __restrict__ feat,
    f16* __restrict__ catW, f16* __restrict__ fc2T, f16* __restrict__ bt2,
    f16* __restrict__ fd2c, f16* __restrict__ wqc, f16* __restrict__ fc1c,
    f16* __restrict__ featb)
{
    __shared__ float t[32][33];
    const int job = blockIdx.z;
    const int tid = threadIdx.x;

    if (job < 4) {
        const float* in; int R, C;
        switch (job) {
            case 0: in = wq;  R = DM_; C = DM_; break;
            case 1: in = wk;  R = DM_; C = DM_; break;
            case 2: in = wv;  R = DM_; C = DM_; break;
            default: in = fc2; R = DM_; C = DP_; break;
        }
        const int c0 = blockIdx.x * 32, r0 = blockIdx.y * 32;
        if (c0 >= C || r0 >= R) return;
        const int lx = tid & 31, ly = tid >> 5;
#pragma unroll
        for (int i = 0; i < 32; i += 8)
            t[ly + i][lx] = in[(size_t)(r0 + ly + i) * C + c0 + lx];
        __syncthreads();
#pragma unroll
        for (int i = 0; i < 32; i += 8) {
            const int c = c0 + ly + i;
            const f16 v = (f16)t[lx][ly + i];
            int n;
            switch (job) {
                case 0: n = c; break;
                case 1: n = 256 + ((c >> 2) << 3) + (c & 3); break;
                case 2: n = 256 + ((c >> 2) << 3) + 4 + (c & 3); break;
                default: n = -1; break;
            }
            if (job < 3) {
                catW[(size_t)n * DM_ + r0 + lx] = v;
            } else {
                fc2T[(size_t)c * DM_ + r0 + lx] = v;
                bt2[(size_t)c * 512 + 256 + r0 + lx] = v;
            }
        }
    } else {
        const int bid = blockIdx.y * 8 + blockIdx.x;
        const int tId = bid * 256 + tid;
        const float* in; f16* outp; int n4;
        if (job == 4)      { in = fd2;  outp = fd2c;  n4 = (DM_ * DM_) / 4; }
        else if (job == 5) { in = wq;   outp = wqc;   n4 = (DM_ * DM_) / 4; }
        else if (job == 6) { in = fc1;  outp = fc1c;  n4 = (DP_ * DM_) / 4; }
        else               { in = feat; outp = featb; n4 = (NPTS * DP_) / 4; }
        for (int i = tId; i < n4; i += 16384) {
            const float4 v = ((const float4*)in)[i];
            const u32 lo = asu32(pkrtz(v.x, v.y));
            const u32 hi = asu32(pkrtz(v.z, v.w));
            ((uint2*)outp)[i] = make_uint2(lo, hi);
        }
    }
}

// ---------------- fused small GEMMs 1: wqp (4 tiles) + bt2 (2 tiles) ----------------
__global__ __launch_bounds__(256) void fused_small1_kernel(
    const f16* __restrict__ fd2c, const f16* __restrict__ wqc,
    f16* __restrict__ catWqp,                   // catW + 768*256
    const f16* __restrict__ fc2T, f16* __restrict__ bt2)
{
    __shared__ __align__(16) f16 As[128 * 32];
    __shared__ __align__(16) f16 Bs[128 * 32];
    const int id = blockIdx.x;
    if (id < 4)
        gemm_tile(As, Bs, fd2c, wqc, nullptr, nullptr, nullptr, catWqp,
                  DM_, DM_, DM_, DM_, id & 1, id >> 1);
    else
        gemm_tile(As, Bs, fc2T, fd2c, nullptr, nullptr, nullptr, bt2,
                  DP_, DM_, DM_, 512, id - 4, 0);
}

// ---------------- fused small GEMMs 2: WallT (8 tiles) + folded biases (5 blocks) ----------------
__global__ __launch_bounds__(256) void fused_small2_kernel(
    const f16* __restrict__ catW, const f16* __restrict__ fc1c, f16* __restrict__ WallT,
    const float* __restrict__ fc1_b, const float* __restrict__ fd2_b,
    const float* __restrict__ fc2_w, const float* __restrict__ fc2_b,
    float* __restrict__ b_all, float* __restrict__ bias2)
{
    __shared__ __align__(16) f16 As[128 * 32];
    __shared__ __align__(16) f16 Bs[128 * 32];
    const int id = blockIdx.x;
    const int tid = threadIdx.x;
    if (id < 8) {
        gemm_tile(As, Bs, catW, fc1c, nullptr, nullptr, nullptr, WallT,
                  1024, DP_, DM_, DP_, 0, id);
    } else if (id < 12) {
        const int n = (id - 8) * 256 + tid;
        float s = 0.0f;
        for (int j = 0; j < DM_; ++j)
            s += fc1_b[j] * (float)catW[(size_t)n * DM_ + j];
        b_all[n] = s;
    } else if (tid < DP_) {
        float s = fc2_b[tid];
        for (int t = 0; t < DM_; ++t)
            s += fd2_b[t] * fc2_w[(size_t)t * DP_ + tid];
        bias2[tid] = s;
    }
}

// ---------------- fused attention: one WAVE per point; fp8 kv gather (8 B/lane/neighbor) ----
// XCD-locality remap: batch = blockIdx & 3, so XCD x (blocks id%8 == x) only touches batch
// x%4's kv8 slab (2 MB <= 4 MB per-XCD L2). Round-15 layout (consecutive ids) spread every
// batch over every XCD -> 8 MB working set per 4 MB L2 -> thrash at the ~5 TB/s L3 ceiling.
__global__ __launch_bounds__(256, 1) void attn_kernel(
    const float* __restrict__ xyz, const f16* __restrict__ qkv,
    const u8* __restrict__ kv8, const int* __restrict__ knn_idx,
    const float* __restrict__ fd1_w, const float* __restrict__ fd1_b,
    const float* __restrict__ fd2_b,
    f16* __restrict__ ab)
{
    const int wave = threadIdx.x >> 6, l = threadIdx.x & 63;
    const int bi = blockIdx.x;
    const int p = ((bi & 3) << 12) + ((bi >> 2) << 2) + wave;   // batch-pinned remap
    const int c0 = l * 4;

    int gi = 0; float dx = 0.0f, dy = 0.0f, dz = 0.0f;
    if (l < 16) {
        gi = knn_idx[p * K_ + l];
        dx = xyz[(size_t)p * 3 + 0] - xyz[(size_t)gi * 3 + 0];
        dy = xyz[(size_t)p * 3 + 1] - xyz[(size_t)gi * 3 + 1];
        dz = xyz[(size_t)p * 3 + 2] - xyz[(size_t)gi * 3 + 2];
    }

    // prefetch ALL 16 neighbor kv8 rows (independent 8B loads), pin above compute
    uint2 kvr8[16];
#pragma unroll
    for (int k = 0; k < 16; ++k) {
        const int gik = __shfl(gi, k);
        kvr8[k] = *(const uint2*)(kv8 + (size_t)gik * 512 + l * 8);
    }
    asm volatile("" ::: "memory");   // loads may not sink past this

    const uint2 qu  = *(const uint2*)(qkv + (size_t)p * 1024 + c0);
    const uint2 qpu = *(const uint2*)(qkv + (size_t)p * 1024 + 768 + c0);
    const h2 qh01 = ash2(qu.x), qh23 = ash2(qu.y);
    const h2 qph01 = ash2(qpu.x), qph23 = ash2(qpu.y);
    const float q0 = (float)qh01.x, q1 = (float)qh01.y, q2 = (float)qh23.x, q3 = (float)qh23.y;
    const float qp0 = (float)qph01.x, qp1 = (float)qph01.y, qp2 = (float)qph23.x, qp3 = (float)qph23.y;

    const float4 w0 = *(const float4*)&fd1_w[c0];
    const float4 w1 = *(const float4*)&fd1_w[DM_ + c0];
    const float4 w2 = *(const float4*)&fd1_w[2 * DM_ + c0];
    const float4 b1 = *(const float4*)&fd1_b[c0];
    const float4 f2b = *(const float4*)&fd2_b[c0];

    // qb = q . fd2_b (constant over k)
    float qb;
    {
        float tq = q0 * f2b.x + q1 * f2b.y + q2 * f2b.z + q3 * f2b.w;
#pragma unroll
        for (int off = 1; off < 64; off <<= 1) tq += __shfl_xor(tq, off);
        qb = tq;
    }

    // phase 1: logits; h packed to f16 and kept for phase 2
    float lg[16];
    u32 h01r[16], h23r[16];
#pragma unroll
    for (int k = 0; k < 16; ++k) {
        const float d0 = __shfl(dx, k), d1 = __shfl(dy, k), d2 = __shfl(dz, k);
        const float h0 = fmaxf(d0 * w0.x + d1 * w1.x + d2 * w2.x + b1.x, 0.0f);
        const float h1 = fmaxf(d0 * w0.y + d1 * w1.y + d2 * w2.y + b1.y, 0.0f);
        const float h2v = fmaxf(d0 * w0.z + d1 * w1.z + d2 * w2.z + b1.z, 0.0f);
        const float h3 = fmaxf(d0 * w0.w + d1 * w1.w + d2 * w2.w + b1.w, 0.0f);
        h01r[k] = asu32(pkrtz(h0, h1));
        h23r[k] = asu32(pkrtz(h2v, h3));
        const auto k01 = __builtin_amdgcn_cvt_pk_f32_fp8((int)kvr8[k].x, false);
        const auto k23 = __builtin_amdgcn_cvt_pk_f32_fp8((int)kvr8[k].x, true);
        float t = q0 * k01[0] + q1 * k01[1] + q2 * k23[0] + q3 * k23[1]
                + h0 * qp0 + h1 * qp1 + h2v * qp2 + h3 * qp3;
#pragma unroll
        for (int off = 1; off < 64; off <<= 1) t += __shfl_xor(t, off);
        lg[k] = t;
    }

    // softmax over 16 (redundant per lane, all registers)
    float att[16];
    {
        float mx = -3.0e38f;
#pragma unroll
        for (int k = 0; k < 16; ++k) {
            att[k] = (lg[k] + qb) * (1.0f / 16.0f);
            mx = fmaxf(mx, att[k]);
        }
        float s = 0.0f;
#pragma unroll
        for (int k = 0; k < 16; ++k) { att[k] = __expf(att[k] - mx); s += att[k]; }
        const float inv = 1.0f / s;
#pragma unroll
        for (int k = 0; k < 16; ++k) att[k] *= inv;
    }

    // phase 2: pure VALU — rbar = sum att*v (kvr8 regs), hbar = sum att*h (regs)
    float rb[4] = {0, 0, 0, 0}, hb[4] = {0, 0, 0, 0};
#pragma unroll
    for (int k = 0; k < 16; ++k) {
        const auto v01 = __builtin_amdgcn_cvt_pk_f32_fp8((int)kvr8[k].y, false);
        const auto v23 = __builtin_amdgcn_cvt_pk_f32_fp8((int)kvr8[k].y, true);
        const h2 hh01 = ash2(h01r[k]), hh23 = ash2(h23r[k]);
        const float a = att[k];
        rb[0] = fmaf(a, v01[0], rb[0]);
        rb[1] = fmaf(a, v01[1], rb[1]);
        rb[2] = fmaf(a, v23[0], rb[2]);
        rb[3] = fmaf(a, v23[1], rb[3]);
        hb[0] = fmaf(a, (float)hh01.x, hb[0]);
        hb[1] = fmaf(a, (float)hh01.y, hb[1]);
        hb[2] = fmaf(a, (float)hh23.x, hb[2]);
        hb[3] = fmaf(a, (float)hh23.y, hb[3]);
    }

    const uint2 ho = make_uint2(asu32(pkrtz(hb[0], hb[1])), asu32(pkrtz(hb[2], hb[3])));
    const uint2 ro = make_uint2(asu32(pkrtz(rb[0], rb[1])), asu32(pkrtz(rb[2], rb[3])));
    *(uint2*)(ab + (size_t)p * 512 + c0) = ho;
    *(uint2*)(ab + (size_t)p * 512 + 256 + c0) = ro;
}

extern "C" void kernel_launch(void* const* d_in, const int* in_sizes, int n_in,
                              void* d_out, int out_size, void* d_ws, size_t ws_size,
                              hipStream_t stream)
{
    const float* features = (const float*)d_in[0];
    const float* xyz   = (const float*)d_in[1];
    const float* fc1_w = (const float*)d_in[2];
    const float* fc1_b = (const float*)d_in[3];
    const float* fc2_w = (const float*)d_in[4];
    const float* fc2_b = (const float*)d_in[5];
    const float* fd1_w = (const float*)d_in[6];
    const float* fd1_b = (const float*)d_in[7];
    const float* fd2_w = (const float*)d_in[8];
    const float* fd2_b = (const float*)d_in[9];
    const float* wq    = (const float*)d_in[10];
    const float* wk    = (const float*)d_in[11];
    const float* wv    = (const float*)d_in[12];
    float* out = (float*)d_out;

    char* base = (char*)d_ws;
    const size_t MB = 1024 * 1024;
    u32*  part = (u32*)(base + 0);                 // 16 MB (16 segs), dead after merge
    f16*  ab   = (f16*)(base + 0);                 // 16 MB [hbar|rbar]
    u8*   kv8  = (u8*)(base + 20 * MB);            // 8 MB fp8 gather buffer
    f16*  qkv  = (f16*)(base + 36 * MB);           // 32 MB
    f16*  featb = (f16*)(base + 68 * MB);          // 4 MB
    int*  idx  = (int*)(base + 72 * MB);           // 1 MB
    char* wb = base + 73 * MB;
    f16* catW  = (f16*)(wb + 0);                   // [1024][256] = 512 KB
    f16* WallT = (f16*)(wb + 512 * 1024);          // [1024][128] = 256 KB
    f16* bt2   = (f16*)(wb + 768 * 1024);          // [128][512]  = 128 KB
    f16* fd2c  = (f16*)(wb + 896 * 1024);
    f16* wqc   = (f16*)(wb + 1024 * 1024);
    f16* fc1c  = (f16*)(wb + 1152 * 1024);
    f16* fc2T  = (f16*)(wb + 1216 * 1024);
    float* b_all = (float*)(wb + 1280 * 1024);
    float* bias2 = (float*)(wb + 1284 * 1024);

    const dim3 blk(256);

    // 1. casts (also seeds bt2 cols [256,512) with fc2^T); k/v rows interleaved in catW
    prep_kernel<<<dim3(8, 8, 8), blk, 0, stream>>>(wq, wk, wv, fd2_w, fc1_w, fc2_w, features,
                                                   catW, fc2T, bt2, fd2c, wqc, fc1c, featb);
    // 2. wqp -> catW rows 768.. (4 tiles) || bt2 cols [0,256) (2 tiles)
    fused_small1_kernel<<<dim3(6), blk, 0, stream>>>(fd2c, wqc, catW + 768 * 256, fc2T, bt2);
    // 3. WallT (8 tiles) || b_all (4) || bias2 (1)
    fused_small2_kernel<<<dim3(13), blk, 0, stream>>>(catW, fc1c, WallT,
                                                      fc1_b, fd2_b, fc2_w, fc2_b, b_all, bias2);
    // 4. KNN partial top-16
    knn_part_kernel<<<dim3(N_ / 256, SEG_, B_), blk, 0, stream>>>(xyz, part);
    // 5. [q | kv-interleaved | qp] = features @ WallT^T + b_all  (K=128, single-barrier)
    gemm_qkv_kernel<<<dim3(1024 / 128, NPTS / 128), blk, 0, stream>>>(featb, WallT, b_all, qkv);
    // 6. kv8 fp8 buffer (4096 blocks) || single-stage 16-segment merge (64 blocks)
    fused_kv8merge_kernel<<<dim3(NPTS * 64 / 256 + NPTS / 256), blk, 0, stream>>>(
        qkv, kv8, part, idx);
    // 7. fused attention -> ab = [hbar | rbar]  (XCD batch-pinned block remap)
    attn_kernel<<<dim3(NPTS / 4), blk, 0, stream>>>(xyz, qkv, kv8, idx,
                                                    fd1_w, fd1_b, fd2_b, ab);
    // 8. out = ab @ bt2^T + bias2 + features, stored TRANSPOSED directly to d_out
    gemm_f16_kernel<<<dim3(1, NPTS / 128), blk, 0, stream>>>(
        ab, bt2, bias2, features, out, nullptr, NPTS, DP_, 512, DP_);

    (void)in_sizes; (void)n_in; (void)out_size; (void)ws_size;
}

// Round 17
// 223.243 us; speedup vs baseline: 1.3579x; 1.1319x over previous
//
#include <hip/hip_runtime.h>
#include <hip/hip_bf16.h>
#include <math.h>

#define B_   4
#define N_   4096
#define K_   16
#define DP_  128
#define DM_  256
#define NPTS (B_ * N_)
#define SEG_ 16
#define CAND_ (N_ / SEG_)   // 256 candidates per segment
#define QPAD 136            // K=128 LDS row stride (f16): 272B, uint4-aligned, low conflict

typedef unsigned int u32;
typedef unsigned char u8;
typedef _Float16 f16;
typedef __attribute__((ext_vector_type(2))) __fp16 h2;     // matches cvt_pkrtz ABI
typedef __attribute__((ext_vector_type(8))) _Float16 f16x8; // MFMA operand
typedef __attribute__((ext_vector_type(4))) float floatx4;

static __device__ __forceinline__ h2 pkrtz(float a, float b) {
    return __builtin_amdgcn_cvt_pkrtz(a, b);
}
static __device__ __forceinline__ u32 asu32(h2 h) { return __builtin_bit_cast(u32, h); }
static __device__ __forceinline__ h2 ash2(u32 u) { return __builtin_bit_cast(h2, u); }

// ---- bitonic primitives on u32 registers ----
#define CEXA(x, y) { u32 _lo = min(x, y); y = max(x, y); x = _lo; }   // x<=y
#define CEXD(x, y) { u32 _hi = max(x, y); y = min(x, y); x = _hi; }   // x>=y

static __device__ __forceinline__ void sort16_desc(u32 c[16]) {
    CEXD(c[0],c[1]);  CEXA(c[2],c[3]);  CEXD(c[4],c[5]);  CEXA(c[6],c[7]);
    CEXD(c[8],c[9]);  CEXA(c[10],c[11]); CEXD(c[12],c[13]); CEXA(c[14],c[15]);

    CEXD(c[0],c[2]);  CEXD(c[1],c[3]);  CEXA(c[4],c[6]);  CEXA(c[5],c[7]);
    CEXD(c[8],c[10]); CEXD(c[9],c[11]); CEXA(c[12],c[14]); CEXA(c[13],c[15]);
    CEXD(c[0],c[1]);  CEXD(c[2],c[3]);  CEXA(c[4],c[5]);  CEXA(c[6],c[7]);
    CEXD(c[8],c[9]);  CEXD(c[10],c[11]); CEXA(c[12],c[13]); CEXA(c[14],c[15]);

    CEXD(c[0],c[4]);  CEXD(c[1],c[5]);  CEXD(c[2],c[6]);  CEXD(c[3],c[7]);
    CEXA(c[8],c[12]); CEXA(c[9],c[13]); CEXA(c[10],c[14]); CEXA(c[11],c[15]);
    CEXD(c[0],c[2]);  CEXD(c[1],c[3]);  CEXD(c[4],c[6]);  CEXD(c[5],c[7]);
    CEXA(c[8],c[10]); CEXA(c[9],c[11]); CEXA(c[12],c[14]); CEXA(c[13],c[15]);
    CEXD(c[0],c[1]);  CEXD(c[2],c[3]);  CEXD(c[4],c[5]);  CEXD(c[6],c[7]);
    CEXA(c[8],c[9]);  CEXA(c[10],c[11]); CEXA(c[12],c[13]); CEXA(c[14],c[15]);

    CEXD(c[0],c[8]);  CEXD(c[1],c[9]);  CEXD(c[2],c[10]); CEXD(c[3],c[11]);
    CEXD(c[4],c[12]); CEXD(c[5],c[13]); CEXD(c[6],c[14]); CEXD(c[7],c[15]);
    CEXD(c[0],c[4]);  CEXD(c[1],c[5]);  CEXD(c[2],c[6]);  CEXD(c[3],c[7]);
    CEXD(c[8],c[12]); CEXD(c[9],c[13]); CEXD(c[10],c[14]); CEXD(c[11],c[15]);
    CEXD(c[0],c[2]);  CEXD(c[1],c[3]);  CEXD(c[4],c[6]);  CEXD(c[5],c[7]);
    CEXD(c[8],c[10]); CEXD(c[9],c[11]); CEXD(c[12],c[14]); CEXD(c[13],c[15]);
    CEXD(c[0],c[1]);  CEXD(c[2],c[3]);  CEXD(c[4],c[5]);  CEXD(c[6],c[7]);
    CEXD(c[8],c[9]);  CEXD(c[10],c[11]); CEXD(c[12],c[13]); CEXD(c[14],c[15]);
}

static __device__ __forceinline__ void remerge16_asc(u32 L[16]) {
    CEXA(L[0],L[8]);  CEXA(L[1],L[9]);  CEXA(L[2],L[10]); CEXA(L[3],L[11]);
    CEXA(L[4],L[12]); CEXA(L[5],L[13]); CEXA(L[6],L[14]); CEXA(L[7],L[15]);
    CEXA(L[0],L[4]);  CEXA(L[1],L[5]);  CEXA(L[2],L[6]);  CEXA(L[3],L[7]);
    CEXA(L[8],L[12]); CEXA(L[9],L[13]); CEXA(L[10],L[14]); CEXA(L[11],L[15]);
    CEXA(L[0],L[2]);  CEXA(L[1],L[3]);  CEXA(L[4],L[6]);  CEXA(L[5],L[7]);
    CEXA(L[8],L[10]); CEXA(L[9],L[11]); CEXA(L[12],L[14]); CEXA(L[13],L[15]);
    CEXA(L[0],L[1]);  CEXA(L[2],L[3]);  CEXA(L[4],L[5]);  CEXA(L[6],L[7]);
    CEXA(L[8],L[9]);  CEXA(L[10],L[11]); CEXA(L[12],L[13]); CEXA(L[14],L[15]);
}

// ---------------- KNN part body: bitonic-batch top-16 per (point, segment) ----------------
static __device__ void knn_part_body(float4* sc, const float* __restrict__ xyz,
                                     u32* __restrict__ part, int id)
{
    const int xblk = id & 15;            // N_/256 = 16
    const int s = (id >> 4) & 15;        // SEG_ = 16
    const int b = id >> 8;               // B_ = 4
    const int n = xblk * 256 + threadIdx.x;
    const float* xb = xyz + (size_t)b * N_ * 3;
    const float nx0 = -xb[n * 3 + 0], nx1 = -xb[n * 3 + 1], nx2 = -xb[n * 3 + 2];
    const u32 kmask = 0xFFFFF000u;

    {
        const int m = s * CAND_ + threadIdx.x;   // CAND_ == 256 == blockDim.x
        const float a0 = xb[m * 3 + 0];
        const float a1 = xb[m * 3 + 1];
        const float a2 = xb[m * 3 + 2];
        sc[threadIdx.x] = make_float4(a0, a1, a2, 0.5f * (a0 * a0 + a1 * a1 + a2 * a2));
    }
    __syncthreads();

    u32 L[16];
#pragma unroll
    for (int i = 0; i < 16; ++i) L[i] = 0xFFFFFFFFu;

    const u32 ibase = (u32)(s * CAND_);
    for (int m0 = 0; m0 < CAND_; m0 += 16) {
        u32 c[16];
#pragma unroll
        for (int t = 0; t < 16; ++t) {
            const float4 cc = sc[m0 + t];
            const float e = fmaf(nx0, cc.x, fmaf(nx1, cc.y, fmaf(nx2, cc.z, cc.w)));
            const int ib = __float_as_int(e);
            const u32 tk = (u32)ib ^ (u32)((ib >> 31) | 0x80000000);
            c[t] = (tk & kmask) | (ibase + (u32)(m0 + t));
        }
        sort16_desc(c);
#pragma unroll
        for (int i = 0; i < 16; ++i) L[i] = min(L[i], c[i]);
        remerge16_asc(L);
    }

    const int p = b * N_ + n;
#pragma unroll
    for (int j = 0; j < 16; ++j)
        part[(size_t)(s * 16 + j) * NPTS + p] = L[j];
}

// ---------------- prep body: weight transpose-casts + straight casts (f16) ----------------
// k/v rows of catW INTERLEAVED: k-col c -> row 256+8*(c/4)+(c%4); v-col c -> +4.
static __device__ void prep_body(float (*t)[33],
    const float* __restrict__ wq, const float* __restrict__ wk, const float* __restrict__ wv,
    const float* __restrict__ fd2, const float* __restrict__ fc1, const float* __restrict__ fc2,
    const float* __restrict__ feat,
    f16* __restrict__ catW, f16* __restrict__ fc2T, f16* __restrict__ bt2,
    f16* __restrict__ fd2c, f16* __restrict__ wqc, f16* __restrict__ fc1c,
    f16* __restrict__ featb, int bx, int by, int job)
{
    const int tid = threadIdx.x;

    if (job < 4) {
        const float* in; int R, C;
        switch (job) {
            case 0: in = wq;  R = DM_; C = DM_; break;
            case 1: in = wk;  R = DM_; C = DM_; break;
            case 2: in = wv;  R = DM_; C = DM_; break;
            default: in = fc2; R = DM_; C = DP_; break;
        }
        const int c0 = bx * 32, r0 = by * 32;
        if (c0 >= C || r0 >= R) return;
        const int lx = tid & 31, ly = tid >> 5;
#pragma unroll
        for (int i = 0; i < 32; i += 8)
            t[ly + i][lx] = in[(size_t)(r0 + ly + i) * C + c0 + lx];
        __syncthreads();
#pragma unroll
        for (int i = 0; i < 32; i += 8) {
            const int c = c0 + ly + i;
            const f16 v = (f16)t[lx][ly + i];
            int n;
            switch (job) {
                case 0: n = c; break;
                case 1: n = 256 + ((c >> 2) << 3) + (c & 3); break;
                case 2: n = 256 + ((c >> 2) << 3) + 4 + (c & 3); break;
                default: n = -1; break;
            }
            if (job < 3) {
                catW[(size_t)n * DM_ + r0 + lx] = v;
            } else {
                fc2T[(size_t)c * DM_ + r0 + lx] = v;
                bt2[(size_t)c * 512 + 256 + r0 + lx] = v;
            }
        }
    } else {
        const int bid = by * 8 + bx;                      // 0..63
        const int tId = bid * 256 + tid;
        const float* in; f16* outp; int n4;
        if (job == 4)      { in = fd2;  outp = fd2c;  n4 = (DM_ * DM_) / 4; }
        else if (job == 5) { in = wq;   outp = wqc;   n4 = (DM_ * DM_) / 4; }
        else if (job == 6) { in = fc1;  outp = fc1c;  n4 = (DP_ * DM_) / 4; }
        else               { in = feat; outp = featb; n4 = (NPTS * DP_) / 4; }
        for (int i = tId; i < n4; i += 16384) {
            const float4 v = ((const float4*)in)[i];
            const u32 lo = asu32(pkrtz(v.x, v.y));
            const u32 hi = asu32(pkrtz(v.z, v.w));
            ((uint2*)outp)[i] = make_uint2(lo, hi);
        }
    }
}

// ---------------- FUSED prep (512 blocks) + knn_part (1024 blocks) ----------------
// Matched footprints: both VGPR <~48, LDS <= 4.4 KB (the r14 failure was mismatch).
__global__ __launch_bounds__(256) void fused_prep_knn_kernel(
    const float* __restrict__ wq, const float* __restrict__ wk, const float* __restrict__ wv,
    const float* __restrict__ fd2, const float* __restrict__ fc1, const float* __restrict__ fc2,
    const float* __restrict__ feat,
    f16* __restrict__ catW, f16* __restrict__ fc2T, f16* __restrict__ bt2,
    f16* __restrict__ fd2c, f16* __restrict__ wqc, f16* __restrict__ fc1c,
    f16* __restrict__ featb,
    const float* __restrict__ xyz, u32* __restrict__ part)
{
    __shared__ __align__(16) char smem[4352];
    const int id = blockIdx.x;
    if (id < 512) {
        prep_body((float(*)[33])smem, wq, wk, wv, fd2, fc1, fc2, feat,
                  catW, fc2T, bt2, fd2c, wqc, fc1c, featb,
                  id & 7, (id >> 3) & 7, id >> 6);
    } else {
        knn_part_body((float4*)smem, xyz, part, id - 512);
    }
}

// ---------------- generic BK=32 GEMM tile (C[M,N] = A@Bt^T, f16 out) ----------------
static __device__ void gemm_tile(f16* As, f16* Bs,
    const f16* __restrict__ A, const f16* __restrict__ Bt,
    f16* __restrict__ Cb,
    int M, int N, int K, int ldc, int bx, int by)
{
    const int tid = threadIdx.x;
    const int m0 = by * 128, n0 = bx * 128;
    const int w = tid >> 6, l = tid & 63;
    const int wm = (w >> 1) * 64, wn = (w & 1) * 64;
    const int fm = l & 15, kq = l >> 4;

    floatx4 acc[4][4];
#pragma unroll
    for (int i = 0; i < 4; ++i)
#pragma unroll
        for (int j = 0; j < 4; ++j)
            acc[i][j] = (floatx4){0.0f, 0.0f, 0.0f, 0.0f};

    for (int k0 = 0; k0 < K; k0 += 32) {
        __syncthreads();
#pragma unroll
        for (int c = 0; c < 2; ++c) {
            const int li = tid + c * 256;
            const int row = li >> 2, part = li & 3;
            *(uint4*)&As[row * 32 + part * 8] =
                *(const uint4*)&A[(size_t)(m0 + row) * K + k0 + part * 8];
            *(uint4*)&Bs[row * 32 + part * 8] =
                *(const uint4*)&Bt[(size_t)(n0 + row) * K + k0 + part * 8];
        }
        __syncthreads();
        f16x8 af[4], bf[4];
#pragma unroll
        for (int i = 0; i < 4; ++i)
            af[i] = *(const f16x8*)&As[(wm + i * 16 + fm) * 32 + kq * 8];
#pragma unroll
        for (int j = 0; j < 4; ++j)
            bf[j] = *(const f16x8*)&Bs[(wn + j * 16 + fm) * 32 + kq * 8];
#pragma unroll
        for (int i = 0; i < 4; ++i)
#pragma unroll
            for (int j = 0; j < 4; ++j)
                acc[i][j] = __builtin_amdgcn_mfma_f32_16x16x32_f16(af[i], bf[j], acc[i][j], 0, 0, 0);
    }

#pragma unroll
    for (int i = 0; i < 4; ++i) {
#pragma unroll
        for (int j = 0; j < 4; ++j) {
            const int col = n0 + wn + j * 16 + fm;
            const int rowb = m0 + wm + i * 16 + kq * 4;
#pragma unroll
            for (int r = 0; r < 4; ++r)
                Cb[(size_t)(rowb + r) * ldc + col] = (f16)acc[i][j][r];
        }
    }
}

// ---------------- qkv GEMM, K=128 fully resident: ONE barrier ----------------
__global__ __launch_bounds__(256) void gemm_qkv_kernel(
    const f16* __restrict__ A,     // featb [NPTS][128]
    const f16* __restrict__ Bt,    // WallT [1024][128]
    const float* __restrict__ bias,
    f16* __restrict__ Cb)          // qkv [NPTS][1024]
{
    __shared__ __align__(16) f16 As[128 * QPAD];
    __shared__ __align__(16) f16 Bs[128 * QPAD];
    const int tid = threadIdx.x;
    const int m0 = blockIdx.y * 128, n0 = blockIdx.x * 128;
    const int w = tid >> 6, l = tid & 63;
    const int wm = (w >> 1) * 64, wn = (w & 1) * 64;
    const int fm = l & 15, kq = l >> 4;

#pragma unroll
    for (int c = 0; c < 8; ++c) {   // 128x128 f16 per matrix = 2048 uint4, 8/thread
        const int li = tid + c * 256;
        const int row = li >> 4, part = li & 15;
        *(uint4*)&As[row * QPAD + part * 8] =
            *(const uint4*)&A[(size_t)(m0 + row) * 128 + part * 8];
        *(uint4*)&Bs[row * QPAD + part * 8] =
            *(const uint4*)&Bt[(size_t)(n0 + row) * 128 + part * 8];
    }
    __syncthreads();

    floatx4 acc[4][4];
#pragma unroll
    for (int i = 0; i < 4; ++i)
#pragma unroll
        for (int j = 0; j < 4; ++j)
            acc[i][j] = (floatx4){0.0f, 0.0f, 0.0f, 0.0f};

#pragma unroll
    for (int kk = 0; kk < 4; ++kk) {
        f16x8 af[4], bf[4];
#pragma unroll
        for (int i = 0; i < 4; ++i)
            af[i] = *(const f16x8*)&As[(wm + i * 16 + fm) * QPAD + kk * 32 + kq * 8];
#pragma unroll
        for (int j = 0; j < 4; ++j)
            bf[j] = *(const f16x8*)&Bs[(wn + j * 16 + fm) * QPAD + kk * 32 + kq * 8];
#pragma unroll
        for (int i = 0; i < 4; ++i)
#pragma unroll
            for (int j = 0; j < 4; ++j)
                acc[i][j] = __builtin_amdgcn_mfma_f32_16x16x32_f16(af[i], bf[j], acc[i][j], 0, 0, 0);
    }

#pragma unroll
    for (int i = 0; i < 4; ++i) {
#pragma unroll
        for (int j = 0; j < 4; ++j) {
            const int col = n0 + wn + j * 16 + fm;
            const int rowb = m0 + wm + i * 16 + kq * 4;
#pragma unroll
            for (int r = 0; r < 4; ++r)
                Cb[(size_t)(rowb + r) * 1024 + col] = (f16)(acc[i][j][r] + bias[col]);
        }
    }
}

// ---------------- out GEMM: 64x128 tile (256 blocks — full CU coverage) ----------------
// out = ab @ bt2^T + bias2 + features, stored TRANSPOSED to [B][DP][N] fp32.
__global__ __launch_bounds__(256) void gemm_out_kernel(
    const f16* __restrict__ A,      // ab [NPTS][512]
    const f16* __restrict__ Bt,     // bt2 [128][512]
    const float* __restrict__ bias2,
    const float* __restrict__ feat, // [NPTS][128] fp32
    float* __restrict__ CT)         // [B][DP][N]
{
    __shared__ __align__(16) f16 As[64 * 32];
    __shared__ __align__(16) f16 Bs[128 * 32];
    const int tid = threadIdx.x;
    const int m0 = blockIdx.x * 64;
    const int w = tid >> 6, l = tid & 63;
    const int wn = w * 32;
    const int fm = l & 15, kq = l >> 4;

    floatx4 acc[4][2];
#pragma unroll
    for (int i = 0; i < 4; ++i)
#pragma unroll
        for (int j = 0; j < 2; ++j)
            acc[i][j] = (floatx4){0.0f, 0.0f, 0.0f, 0.0f};

    for (int k0 = 0; k0 < 512; k0 += 32) {
        __syncthreads();
        {   // stage A: 64x32 = 256 uint4, 1/thread
            const int row = tid >> 2, part = tid & 3;
            *(uint4*)&As[row * 32 + part * 8] =
                *(const uint4*)&A[(size_t)(m0 + row) * 512 + k0 + part * 8];
        }
#pragma unroll
        for (int c = 0; c < 2; ++c) {   // stage B: 128x32 = 512 uint4, 2/thread
            const int li = tid + c * 256;
            const int row = li >> 2, part = li & 3;
            *(uint4*)&Bs[row * 32 + part * 8] =
                *(const uint4*)&Bt[(size_t)row * 512 + k0 + part * 8];
        }
        __syncthreads();
        f16x8 af[4], bf[2];
#pragma unroll
        for (int i = 0; i < 4; ++i)
            af[i] = *(const f16x8*)&As[(i * 16 + fm) * 32 + kq * 8];
#pragma unroll
        for (int j = 0; j < 2; ++j)
            bf[j] = *(const f16x8*)&Bs[(wn + j * 16 + fm) * 32 + kq * 8];
#pragma unroll
        for (int i = 0; i < 4; ++i)
#pragma unroll
            for (int j = 0; j < 2; ++j)
                acc[i][j] = __builtin_amdgcn_mfma_f32_16x16x32_f16(af[i], bf[j], acc[i][j], 0, 0, 0);
    }

#pragma unroll
    for (int i = 0; i < 4; ++i) {
#pragma unroll
        for (int j = 0; j < 2; ++j) {
            const int col = wn + j * 16 + fm;
            const int rowb = m0 + i * 16 + kq * 4;
            float4 vv;
#pragma unroll
            for (int r = 0; r < 4; ++r)
                ((float*)&vv)[r] = acc[i][j][r] + bias2[col]
                                 + feat[(size_t)(rowb + r) * DP_ + col];
            const int bb = rowb >> 12;
            *(float4*)&CT[(size_t)(bb * DP_ + col) * N_ + (rowb & (N_ - 1))] = vv;
        }
    }
}

// ---------------- kv8 body + single-stage mergeAB body, FUSED ----------------
static __device__ void kv8_body(const f16* __restrict__ qkv, u8* __restrict__ kv8, int id)
{
    const int t = id * 256 + threadIdx.x;   // 0 .. NPTS*64-1
    const int p = t >> 6, g = t & 63;
    const uint4 kv = *(const uint4*)(qkv + (size_t)p * 1024 + 256 + g * 8);
    const h2 k01 = ash2(kv.x), k23 = ash2(kv.y), v01 = ash2(kv.z), v23 = ash2(kv.w);
    int lo = 0, hi = 0;
    lo = __builtin_amdgcn_cvt_pk_fp8_f32((float)k01.x, (float)k01.y, lo, false);
    lo = __builtin_amdgcn_cvt_pk_fp8_f32((float)k23.x, (float)k23.y, lo, true);
    hi = __builtin_amdgcn_cvt_pk_fp8_f32((float)v01.x, (float)v01.y, hi, false);
    hi = __builtin_amdgcn_cvt_pk_fp8_f32((float)v23.x, (float)v23.y, hi, true);
    *(uint2*)(kv8 + (size_t)p * 512 + g * 8) = make_uint2((u32)lo, (u32)hi);
}

static __device__ void mergeAB_body(const u32* __restrict__ part, int* __restrict__ knn_idx,
                                    int id)
{
    const int p = id * 256 + threadIdx.x;   // global point id
    const int b = p >> 12;

    u32 L[16];
#pragma unroll
    for (int i = 0; i < 16; ++i) L[i] = 0xFFFFFFFFu;

    for (int s = 0; s < SEG_; ++s) {
        u32 seg[16];
#pragma unroll
        for (int j = 0; j < 16; ++j)
            seg[j] = part[(size_t)(s * 16 + j) * NPTS + p];
#pragma unroll
        for (int i = 0; i < 16; ++i) L[i] = min(L[i], seg[15 - i]);
        remerge16_asc(L);
    }

    int* o = knn_idx + (size_t)p * K_;
#pragma unroll
    for (int i = 0; i < 16; ++i) o[i] = b * N_ + (int)(L[i] & 0xFFFu);
}

__global__ __launch_bounds__(256) void fused_kv8merge_kernel(
    const f16* __restrict__ qkv, u8* __restrict__ kv8,
    const u32* __restrict__ part, int* __restrict__ knn_idx)
{
    const int id = blockIdx.x;
    if (id < NPTS * 64 / 256) kv8_body(qkv, kv8, id);
    else                      mergeAB_body(part, knn_idx, id - NPTS * 64 / 256);
}

// ---------------- fused small GEMMs 1: wqp (4 tiles) + bt2 (2 tiles) ----------------
__global__ __launch_bounds__(256) void fused_small1_kernel(
    const f16* __restrict__ fd2c, const f16* __restrict__ wqc,
    f16* __restrict__ catWqp,                   // catW + 768*256
    const f16* __restrict__ fc2T, f16* __restrict__ bt2)
{
    __shared__ __align__(16) f16 As[128 * 32];
    __shared__ __align__(16) f16 Bs[128 * 32];
    const int id = blockIdx.x;
    if (id < 4)
        gemm_tile(As, Bs, fd2c, wqc, catWqp, DM_, DM_, DM_, DM_, id & 1, id >> 1);
    else
        gemm_tile(As, Bs, fc2T, fd2c, bt2, DP_, DM_, DM_, 512, id - 4, 0);
}

// ---------------- fused small GEMMs 2: WallT (8 tiles) + folded biases (5 blocks) ----------------
__global__ __launch_bounds__(256) void fused_small2_kernel(
    const f16* __restrict__ catW, const f16* __restrict__ fc1c, f16* __restrict__ WallT,
    const float* __restrict__ fc1_b, const float* __restrict__ fd2_b,
    const float* __restrict__ fc2_w, const float* __restrict__ fc2_b,
    float* __restrict__ b_all, float* __restrict__ bias2)
{
    __shared__ __align__(16) f16 As[128 * 32];
    __shared__ __align__(16) f16 Bs[128 * 32];
    const int id = blockIdx.x;
    const int tid = threadIdx.x;
    if (id < 8) {
        gemm_tile(As, Bs, catW, fc1c, WallT, 1024, DP_, DM_, DP_, 0, id);
    } else if (id < 12) {
        const int n = (id - 8) * 256 + tid;
        float s = 0.0f;
        for (int j = 0; j < DM_; ++j)
            s += fc1_b[j] * (float)catW[(size_t)n * DM_ + j];
        b_all[n] = s;
    } else if (tid < DP_) {
        float s = fc2_b[tid];
        for (int t = 0; t < DM_; ++t)
            s += fd2_b[t] * fc2_w[(size_t)t * DP_ + tid];
        bias2[tid] = s;
    }
}

// ---------------- fused attention: one WAVE per point; fp8 kv gather; XCD-pinned remap ----
__global__ __launch_bounds__(256, 1) void attn_kernel(
    const float* __restrict__ xyz, const f16* __restrict__ qkv,
    const u8* __restrict__ kv8, const int* __restrict__ knn_idx,
    const float* __restrict__ fd1_w, const float* __restrict__ fd1_b,
    const float* __restrict__ fd2_b,
    f16* __restrict__ ab)
{
    const int wave = threadIdx.x >> 6, l = threadIdx.x & 63;
    const int bi = blockIdx.x;
    const int p = ((bi & 3) << 12) + ((bi >> 2) << 2) + wave;   // batch-pinned remap
    const int c0 = l * 4;

    int gi = 0; float dx = 0.0f, dy = 0.0f, dz = 0.0f;
    if (l < 16) {
        gi = knn_idx[p * K_ + l];
        dx = xyz[(size_t)p * 3 + 0] - xyz[(size_t)gi * 3 + 0];
        dy = xyz[(size_t)p * 3 + 1] - xyz[(size_t)gi * 3 + 1];
        dz = xyz[(size_t)p * 3 + 2] - xyz[(size_t)gi * 3 + 2];
    }

    // prefetch ALL 16 neighbor kv8 rows (independent 8B loads), pin above compute
    uint2 kvr8[16];
#pragma unroll
    for (int k = 0; k < 16; ++k) {
        const int gik = __shfl(gi, k);
        kvr8[k] = *(const uint2*)(kv8 + (size_t)gik * 512 + l * 8);
    }
    asm volatile("" ::: "memory");   // loads may not sink past this

    const uint2 qu  = *(const uint2*)(qkv + (size_t)p * 1024 + c0);
    const uint2 qpu = *(const uint2*)(qkv + (size_t)p * 1024 + 768 + c0);
    const h2 qh01 = ash2(qu.x), qh23 = ash2(qu.y);
    const h2 qph01 = ash2(qpu.x), qph23 = ash2(qpu.y);
    const float q0 = (float)qh01.x, q1 = (float)qh01.y, q2 = (float)qh23.x, q3 = (float)qh23.y;
    const float qp0 = (float)qph01.x, qp1 = (float)qph01.y, qp2 = (float)qph23.x, qp3 = (float)qph23.y;

    const float4 w0 = *(const float4*)&fd1_w[c0];
    const float4 w1 = *(const float4*)&fd1_w[DM_ + c0];
    const float4 w2 = *(const float4*)&fd1_w[2 * DM_ + c0];
    const float4 b1 = *(const float4*)&fd1_b[c0];
    const float4 f2b = *(const float4*)&fd2_b[c0];

    // qb = q . fd2_b (constant over k)
    float qb;
    {
        float tq = q0 * f2b.x + q1 * f2b.y + q2 * f2b.z + q3 * f2b.w;
#pragma unroll
        for (int off = 1; off < 64; off <<= 1) tq += __shfl_xor(tq, off);
        qb = tq;
    }

    // phase 1: logits; h packed to f16 and kept for phase 2
    float lg[16];
    u32 h01r[16], h23r[16];
#pragma unroll
    for (int k = 0; k < 16; ++k) {
        const float d0 = __shfl(dx, k), d1 = __shfl(dy, k), d2 = __shfl(dz, k);
        const float h0 = fmaxf(d0 * w0.x + d1 * w1.x + d2 * w2.x + b1.x, 0.0f);
        const float h1 = fmaxf(d0 * w0.y + d1 * w1.y + d2 * w2.y + b1.y, 0.0f);
        const float h2v = fmaxf(d0 * w0.z + d1 * w1.z + d2 * w2.z + b1.z, 0.0f);
        const float h3 = fmaxf(d0 * w0.w + d1 * w1.w + d2 * w2.w + b1.w, 0.0f);
        h01r[k] = asu32(pkrtz(h0, h1));
        h23r[k] = asu32(pkrtz(h2v, h3));
        const auto k01 = __builtin_amdgcn_cvt_pk_f32_fp8((int)kvr8[k].x, false);
        const auto k23 = __builtin_amdgcn_cvt_pk_f32_fp8((int)kvr8[k].x, true);
        float t = q0 * k01[0] + q1 * k01[1] + q2 * k23[0] + q3 * k23[1]
                + h0 * qp0 + h1 * qp1 + h2v * qp2 + h3 * qp3;
#pragma unroll
        for (int off = 1; off < 64; off <<= 1) t += __shfl_xor(t, off);
        lg[k] = t;
    }

    // softmax over 16 (redundant per lane, all registers)
    float att[16];
    {
        float mx = -3.0e38f;
#pragma unroll
        for (int k = 0; k < 16; ++k) {
            att[k] = (lg[k] + qb) * (1.0f / 16.0f);
            mx = fmaxf(mx, att[k]);
        }
        float s = 0.0f;
#pragma unroll
        for (int k = 0; k < 16; ++k) { att[k] = __expf(att[k] - mx); s += att[k]; }
        const float inv = 1.0f / s;
#pragma unroll
        for (int k = 0; k < 16; ++k) att[k] *= inv;
    }

    // phase 2: pure VALU — rbar = sum att*v (kvr8 regs), hbar = sum att*h (regs)
    float rb[4] = {0, 0, 0, 0}, hb[4] = {0, 0, 0, 0};
#pragma unroll
    for (int k = 0; k < 16; ++k) {
        const auto v01 = __builtin_amdgcn_cvt_pk_f32_fp8((int)kvr8[k].y, false);
        const auto v23 = __builtin_amdgcn_cvt_pk_f32_fp8((int)kvr8[k].y, true);
        const h2 hh01 = ash2(h01r[k]), hh23 = ash2(h23r[k]);
        const float a = att[k];
        rb[0] = fmaf(a, v01[0], rb[0]);
        rb[1] = fmaf(a, v01[1], rb[1]);
        rb[2] = fmaf(a, v23[0], rb[2]);
        rb[3] = fmaf(a, v23[1], rb[3]);
        hb[0] = fmaf(a, (float)hh01.x, hb[0]);
        hb[1] = fmaf(a, (float)hh01.y, hb[1]);
        hb[2] = fmaf(a, (float)hh23.x, hb[2]);
        hb[3] = fmaf(a, (float)hh23.y, hb[3]);
    }

    const uint2 ho = make_uint2(asu32(pkrtz(hb[0], hb[1])), asu32(pkrtz(hb[2], hb[3])));
    const uint2 ro = make_uint2(asu32(pkrtz(rb[0], rb[1])), asu32(pkrtz(rb[2], rb[3])));
    *(uint2*)(ab + (size_t)p * 512 + c0) = ho;
    *(uint2*)(ab + (size_t)p * 512 + 256 + c0) = ro;
}

extern "C" void kernel_launch(void* const* d_in, const int* in_sizes, int n_in,
                              void* d_out, int out_size, void* d_ws, size_t ws_size,
                              hipStream_t stream)
{
    const float* features = (const float*)d_in[0];
    const float* xyz   = (const float*)d_in[1];
    const float* fc1_w = (const float*)d_in[2];
    const float* fc1_b = (const float*)d_in[3];
    const float* fc2_w = (const float*)d_in[4];
    const float* fc2_b = (const float*)d_in[5];
    const float* fd1_w = (const float*)d_in[6];
    const float* fd1_b = (const float*)d_in[7];
    const float* fd2_w = (const float*)d_in[8];
    const float* fd2_b = (const float*)d_in[9];
    const float* wq    = (const float*)d_in[10];
    const float* wk    = (const float*)d_in[11];
    const float* wv    = (const float*)d_in[12];
    float* out = (float*)d_out;

    char* base = (char*)d_ws;
    const size_t MB = 1024 * 1024;
    u32*  part = (u32*)(base + 0);                 // 16 MB (16 segs), dead after merge
    f16*  ab   = (f16*)(base + 0);                 // 16 MB [hbar|rbar]
    u8*   kv8  = (u8*)(base + 20 * MB);            // 8 MB fp8 gather buffer
    f16*  qkv  = (f16*)(base + 36 * MB);           // 32 MB
    f16*  featb = (f16*)(base + 68 * MB);          // 4 MB
    int*  idx  = (int*)(base + 72 * MB);           // 1 MB
    char* wb = base + 73 * MB;
    f16* catW  = (f16*)(wb + 0);                   // [1024][256] = 512 KB
    f16* WallT = (f16*)(wb + 512 * 1024);          // [1024][128] = 256 KB
    f16* bt2   = (f16*)(wb + 768 * 1024);          // [128][512]  = 128 KB
    f16* fd2c  = (f16*)(wb + 896 * 1024);
    f16* wqc   = (f16*)(wb + 1024 * 1024);
    f16* fc1c  = (f16*)(wb + 1152 * 1024);
    f16* fc2T  = (f16*)(wb + 1216 * 1024);
    float* b_all = (float*)(wb + 1280 * 1024);
    float* bias2 = (float*)(wb + 1284 * 1024);

    const dim3 blk(256);

    // 1. prep casts (512 blocks) || KNN partial top-16 (1024 blocks) — independent
    fused_prep_knn_kernel<<<dim3(512 + 1024), blk, 0, stream>>>(
        wq, wk, wv, fd2_w, fc1_w, fc2_w, features,
        catW, fc2T, bt2, fd2c, wqc, fc1c, featb, xyz, part);
    // 2. wqp -> catW rows 768.. (4 tiles) || bt2 cols [0,256) (2 tiles)
    fused_small1_kernel<<<dim3(6), blk, 0, stream>>>(fd2c, wqc, catW + 768 * 256, fc2T, bt2);
    // 3. WallT (8 tiles) || b_all (4) || bias2 (1)
    fused_small2_kernel<<<dim3(13), blk, 0, stream>>>(catW, fc1c, WallT,
                                                      fc1_b, fd2_b, fc2_w, fc2_b, b_all, bias2);
    // 4. [q | kv-interleaved | qp] = features @ WallT^T + b_all  (K=128, single-barrier)
    gemm_qkv_kernel<<<dim3(1024 / 128, NPTS / 128), blk, 0, stream>>>(featb, WallT, b_all, qkv);
    // 5. kv8 fp8 buffer (4096 blocks) || single-stage 16-segment merge (64 blocks)
    fused_kv8merge_kernel<<<dim3(NPTS * 64 / 256 + NPTS / 256), blk, 0, stream>>>(
        qkv, kv8, part, idx);
    // 6. fused attention -> ab = [hbar | rbar]  (XCD batch-pinned block remap)
    attn_kernel<<<dim3(NPTS / 4), blk, 0, stream>>>(xyz, qkv, kv8, idx,
                                                    fd1_w, fd1_b, fd2_b, ab);
    // 7. out GEMM: 64x128 tiles -> 256 blocks, fused transpose + bias + residual
    gemm_out_kernel<<<dim3(NPTS / 64), blk, 0, stream>>>(ab, bt2, bias2, features, out);

    (void)in_sizes; (void)n_in; (void)out_size; (void)ws_size;
}

// Round 18
// 214.086 us; speedup vs baseline: 1.4160x; 1.0428x over previous
//
#include <hip/hip_runtime.h>
#include <hip/hip_bf16.h>
#include <hip/hip_fp16.h>
#include <math.h>

#define B_   4
#define N_   4096
#define K_   16
#define DP_  128
#define DM_  256
#define NPTS (B_ * N_)
#define SEG_ 16
#define CAND_ (N_ / SEG_)   // 256 candidates per segment
#define QPAD 136            // K=128 LDS row stride (f16): 272B, uint4-aligned, low conflict

typedef unsigned int u32;
typedef unsigned char u8;
typedef _Float16 f16;
typedef __attribute__((ext_vector_type(2))) __fp16 h2;     // matches cvt_pkrtz ABI
typedef __attribute__((ext_vector_type(8))) _Float16 f16x8; // MFMA operand
typedef __attribute__((ext_vector_type(4))) float floatx4;

static __device__ __forceinline__ h2 pkrtz(float a, float b) {
    return __builtin_amdgcn_cvt_pkrtz(a, b);
}
static __device__ __forceinline__ u32 asu32(h2 h) { return __builtin_bit_cast(u32, h); }
static __device__ __forceinline__ h2 ash2(u32 u) { return __builtin_bit_cast(h2, u); }

// ---- bitonic primitives on u32 registers ----
#define CEXA(x, y) { u32 _lo = min(x, y); y = max(x, y); x = _lo; }   // x<=y
#define CEXD(x, y) { u32 _hi = max(x, y); y = min(x, y); x = _hi; }   // x>=y

static __device__ __forceinline__ void sort16_desc(u32 c[16]) {
    CEXD(c[0],c[1]);  CEXA(c[2],c[3]);  CEXD(c[4],c[5]);  CEXA(c[6],c[7]);
    CEXD(c[8],c[9]);  CEXA(c[10],c[11]); CEXD(c[12],c[13]); CEXA(c[14],c[15]);

    CEXD(c[0],c[2]);  CEXD(c[1],c[3]);  CEXA(c[4],c[6]);  CEXA(c[5],c[7]);
    CEXD(c[8],c[10]); CEXD(c[9],c[11]); CEXA(c[12],c[14]); CEXA(c[13],c[15]);
    CEXD(c[0],c[1]);  CEXD(c[2],c[3]);  CEXA(c[4],c[5]);  CEXA(c[6],c[7]);
    CEXD(c[8],c[9]);  CEXD(c[10],c[11]); CEXA(c[12],c[13]); CEXA(c[14],c[15]);

    CEXD(c[0],c[4]);  CEXD(c[1],c[5]);  CEXD(c[2],c[6]);  CEXD(c[3],c[7]);
    CEXA(c[8],c[12]); CEXA(c[9],c[13]); CEXA(c[10],c[14]); CEXA(c[11],c[15]);
    CEXD(c[0],c[2]);  CEXD(c[1],c[3]);  CEXD(c[4],c[6]);  CEXD(c[5],c[7]);
    CEXA(c[8],c[10]); CEXA(c[9],c[11]); CEXA(c[12],c[14]); CEXA(c[13],c[15]);
    CEXD(c[0],c[1]);  CEXD(c[2],c[3]);  CEXD(c[4],c[5]);  CEXD(c[6],c[7]);
    CEXA(c[8],c[9]);  CEXA(c[10],c[11]); CEXA(c[12],c[13]); CEXA(c[14],c[15]);

    CEXD(c[0],c[8]);  CEXD(c[1],c[9]);  CEXD(c[2],c[10]); CEXD(c[3],c[11]);
    CEXD(c[4],c[12]); CEXD(c[5],c[13]); CEXD(c[6],c[14]); CEXD(c[7],c[15]);
    CEXD(c[0],c[4]);  CEXD(c[1],c[5]);  CEXD(c[2],c[6]);  CEXD(c[3],c[7]);
    CEXD(c[8],c[12]); CEXD(c[9],c[13]); CEXD(c[10],c[14]); CEXD(c[11],c[15]);
    CEXD(c[0],c[2]);  CEXD(c[1],c[3]);  CEXD(c[4],c[6]);  CEXD(c[5],c[7]);
    CEXD(c[8],c[10]); CEXD(c[9],c[11]); CEXD(c[12],c[14]); CEXD(c[13],c[15]);
    CEXD(c[0],c[1]);  CEXD(c[2],c[3]);  CEXD(c[4],c[5]);  CEXD(c[6],c[7]);
    CEXD(c[8],c[9]);  CEXD(c[10],c[11]); CEXD(c[12],c[13]); CEXD(c[14],c[15]);
}

static __device__ __forceinline__ void remerge16_asc(u32 L[16]) {
    CEXA(L[0],L[8]);  CEXA(L[1],L[9]);  CEXA(L[2],L[10]); CEXA(L[3],L[11]);
    CEXA(L[4],L[12]); CEXA(L[5],L[13]); CEXA(L[6],L[14]); CEXA(L[7],L[15]);
    CEXA(L[0],L[4]);  CEXA(L[1],L[5]);  CEXA(L[2],L[6]);  CEXA(L[3],L[7]);
    CEXA(L[8],L[12]); CEXA(L[9],L[13]); CEXA(L[10],L[14]); CEXA(L[11],L[15]);
    CEXA(L[0],L[2]);  CEXA(L[1],L[3]);  CEXA(L[4],L[6]);  CEXA(L[5],L[7]);
    CEXA(L[8],L[10]); CEXA(L[9],L[11]); CEXA(L[12],L[14]); CEXA(L[13],L[15]);
    CEXA(L[0],L[1]);  CEXA(L[2],L[3]);  CEXA(L[4],L[5]);  CEXA(L[6],L[7]);
    CEXA(L[8],L[9]);  CEXA(L[10],L[11]); CEXA(L[12],L[13]); CEXA(L[14],L[15]);
}

// ---------------- KNN part body: bitonic-batch top-16 per (point, segment) ----------------
static __device__ void knn_part_body(float4* sc, const float* __restrict__ xyz,
                                     u32* __restrict__ part, int id)
{
    const int xblk = id & 15;            // N_/256 = 16
    const int s = (id >> 4) & 15;        // SEG_ = 16
    const int b = id >> 8;               // B_ = 4
    const int n = xblk * 256 + threadIdx.x;
    const float* xb = xyz + (size_t)b * N_ * 3;
    const float nx0 = -xb[n * 3 + 0], nx1 = -xb[n * 3 + 1], nx2 = -xb[n * 3 + 2];
    const u32 kmask = 0xFFFFF000u;

    {
        const int m = s * CAND_ + threadIdx.x;   // CAND_ == 256 == blockDim.x
        const float a0 = xb[m * 3 + 0];
        const float a1 = xb[m * 3 + 1];
        const float a2 = xb[m * 3 + 2];
        sc[threadIdx.x] = make_float4(a0, a1, a2, 0.5f * (a0 * a0 + a1 * a1 + a2 * a2));
    }
    __syncthreads();

    u32 L[16];
#pragma unroll
    for (int i = 0; i < 16; ++i) L[i] = 0xFFFFFFFFu;

    const u32 ibase = (u32)(s * CAND_);
    for (int m0 = 0; m0 < CAND_; m0 += 16) {
        u32 c[16];
#pragma unroll
        for (int t = 0; t < 16; ++t) {
            const float4 cc = sc[m0 + t];
            const float e = fmaf(nx0, cc.x, fmaf(nx1, cc.y, fmaf(nx2, cc.z, cc.w)));
            const int ib = __float_as_int(e);
            const u32 tk = (u32)ib ^ (u32)((ib >> 31) | 0x80000000);
            c[t] = (tk & kmask) | (ibase + (u32)(m0 + t));
        }
        sort16_desc(c);
#pragma unroll
        for (int i = 0; i < 16; ++i) L[i] = min(L[i], c[i]);
        remerge16_asc(L);
    }

    const int p = b * N_ + n;
#pragma unroll
    for (int j = 0; j < 16; ++j)
        part[(size_t)(s * 16 + j) * NPTS + p] = L[j];
}

// ---------------- prep body: weight transpose-casts + straight casts (f16) ----------------
static __device__ void prep_body(float (*t)[33],
    const float* __restrict__ wq, const float* __restrict__ wk, const float* __restrict__ wv,
    const float* __restrict__ fd2, const float* __restrict__ fc1, const float* __restrict__ fc2,
    const float* __restrict__ feat,
    f16* __restrict__ catW, f16* __restrict__ fc2T, f16* __restrict__ bt2,
    f16* __restrict__ fd2c, f16* __restrict__ wqc, f16* __restrict__ fc1c,
    f16* __restrict__ featb, int bx, int by, int job)
{
    const int tid = threadIdx.x;

    if (job < 4) {
        const float* in; int R, C;
        switch (job) {
            case 0: in = wq;  R = DM_; C = DM_; break;
            case 1: in = wk;  R = DM_; C = DM_; break;
            case 2: in = wv;  R = DM_; C = DM_; break;
            default: in = fc2; R = DM_; C = DP_; break;
        }
        const int c0 = bx * 32, r0 = by * 32;
        if (c0 >= C || r0 >= R) return;
        const int lx = tid & 31, ly = tid >> 5;
#pragma unroll
        for (int i = 0; i < 32; i += 8)
            t[ly + i][lx] = in[(size_t)(r0 + ly + i) * C + c0 + lx];
        __syncthreads();
#pragma unroll
        for (int i = 0; i < 32; i += 8) {
            const int c = c0 + ly + i;
            const f16 v = (f16)t[lx][ly + i];
            int n;
            switch (job) {
                case 0: n = c; break;
                case 1: n = 256 + ((c >> 2) << 3) + (c & 3); break;
                case 2: n = 256 + ((c >> 2) << 3) + 4 + (c & 3); break;
                default: n = -1; break;
            }
            if (job < 3) {
                catW[(size_t)n * DM_ + r0 + lx] = v;
            } else {
                fc2T[(size_t)c * DM_ + r0 + lx] = v;
                bt2[(size_t)c * 512 + 256 + r0 + lx] = v;
            }
        }
    } else {
        const int bid = by * 8 + bx;                      // 0..63
        const int tId = bid * 256 + tid;
        const float* in; f16* outp; int n4;
        if (job == 4)      { in = fd2;  outp = fd2c;  n4 = (DM_ * DM_) / 4; }
        else if (job == 5) { in = wq;   outp = wqc;   n4 = (DM_ * DM_) / 4; }
        else if (job == 6) { in = fc1;  outp = fc1c;  n4 = (DP_ * DM_) / 4; }
        else               { in = feat; outp = featb; n4 = (NPTS * DP_) / 4; }
        for (int i = tId; i < n4; i += 16384) {
            const float4 v = ((const float4*)in)[i];
            const u32 lo = asu32(pkrtz(v.x, v.y));
            const u32 hi = asu32(pkrtz(v.z, v.w));
            ((uint2*)outp)[i] = make_uint2(lo, hi);
        }
    }
}

// ---------------- FUSED prep (512 blocks) + knn_part (1024 blocks) ----------------
__global__ __launch_bounds__(256) void fused_prep_knn_kernel(
    const float* __restrict__ wq, const float* __restrict__ wk, const float* __restrict__ wv,
    const float* __restrict__ fd2, const float* __restrict__ fc1, const float* __restrict__ fc2,
    const float* __restrict__ feat,
    f16* __restrict__ catW, f16* __restrict__ fc2T, f16* __restrict__ bt2,
    f16* __restrict__ fd2c, f16* __restrict__ wqc, f16* __restrict__ fc1c,
    f16* __restrict__ featb,
    const float* __restrict__ xyz, u32* __restrict__ part)
{
    __shared__ __align__(16) char smem[4352];
    const int id = blockIdx.x;
    if (id < 512) {
        prep_body((float(*)[33])smem, wq, wk, wv, fd2, fc1, fc2, feat,
                  catW, fc2T, bt2, fd2c, wqc, fc1c, featb,
                  id & 7, (id >> 3) & 7, id >> 6);
    } else {
        knn_part_body((float4*)smem, xyz, part, id - 512);
    }
}

// ---------------- generic BK=32 GEMM tile (C[M,N] = A@Bt^T, f16 out) ----------------
static __device__ void gemm_tile(f16* As, f16* Bs,
    const f16* __restrict__ A, const f16* __restrict__ Bt,
    f16* __restrict__ Cb,
    int M, int N, int K, int ldc, int bx, int by)
{
    const int tid = threadIdx.x;
    const int m0 = by * 128, n0 = bx * 128;
    const int w = tid >> 6, l = tid & 63;
    const int wm = (w >> 1) * 64, wn = (w & 1) * 64;
    const int fm = l & 15, kq = l >> 4;

    floatx4 acc[4][4];
#pragma unroll
    for (int i = 0; i < 4; ++i)
#pragma unroll
        for (int j = 0; j < 4; ++j)
            acc[i][j] = (floatx4){0.0f, 0.0f, 0.0f, 0.0f};

    for (int k0 = 0; k0 < K; k0 += 32) {
        __syncthreads();
#pragma unroll
        for (int c = 0; c < 2; ++c) {
            const int li = tid + c * 256;
            const int row = li >> 2, part = li & 3;
            *(uint4*)&As[row * 32 + part * 8] =
                *(const uint4*)&A[(size_t)(m0 + row) * K + k0 + part * 8];
            *(uint4*)&Bs[row * 32 + part * 8] =
                *(const uint4*)&Bt[(size_t)(n0 + row) * K + k0 + part * 8];
        }
        __syncthreads();
        f16x8 af[4], bf[4];
#pragma unroll
        for (int i = 0; i < 4; ++i)
            af[i] = *(const f16x8*)&As[(wm + i * 16 + fm) * 32 + kq * 8];
#pragma unroll
        for (int j = 0; j < 4; ++j)
            bf[j] = *(const f16x8*)&Bs[(wn + j * 16 + fm) * 32 + kq * 8];
#pragma unroll
        for (int i = 0; i < 4; ++i)
#pragma unroll
            for (int j = 0; j < 4; ++j)
                acc[i][j] = __builtin_amdgcn_mfma_f32_16x16x32_f16(af[i], bf[j], acc[i][j], 0, 0, 0);
    }

#pragma unroll
    for (int i = 0; i < 4; ++i) {
#pragma unroll
        for (int j = 0; j < 4; ++j) {
            const int col = n0 + wn + j * 16 + fm;
            const int rowb = m0 + wm + i * 16 + kq * 4;
#pragma unroll
            for (int r = 0; r < 4; ++r)
                Cb[(size_t)(rowb + r) * ldc + col] = (f16)acc[i][j][r];
        }
    }
}

// ---------------- qkv GEMM, K=128 fully resident: ONE barrier ----------------
__global__ __launch_bounds__(256) void gemm_qkv_kernel(
    const f16* __restrict__ A,     // featb [NPTS][128]
    const f16* __restrict__ Bt,    // WallT [1024][128]
    const float* __restrict__ bias,
    f16* __restrict__ Cb)          // qkv [NPTS][1024]
{
    __shared__ __align__(16) f16 As[128 * QPAD];
    __shared__ __align__(16) f16 Bs[128 * QPAD];
    const int tid = threadIdx.x;
    const int m0 = blockIdx.y * 128, n0 = blockIdx.x * 128;
    const int w = tid >> 6, l = tid & 63;
    const int wm = (w >> 1) * 64, wn = (w & 1) * 64;
    const int fm = l & 15, kq = l >> 4;

#pragma unroll
    for (int c = 0; c < 8; ++c) {
        const int li = tid + c * 256;
        const int row = li >> 4, part = li & 15;
        *(uint4*)&As[row * QPAD + part * 8] =
            *(const uint4*)&A[(size_t)(m0 + row) * 128 + part * 8];
        *(uint4*)&Bs[row * QPAD + part * 8] =
            *(const uint4*)&Bt[(size_t)(n0 + row) * 128 + part * 8];
    }
    __syncthreads();

    floatx4 acc[4][4];
#pragma unroll
    for (int i = 0; i < 4; ++i)
#pragma unroll
        for (int j = 0; j < 4; ++j)
            acc[i][j] = (floatx4){0.0f, 0.0f, 0.0f, 0.0f};

#pragma unroll
    for (int kk = 0; kk < 4; ++kk) {
        f16x8 af[4], bf[4];
#pragma unroll
        for (int i = 0; i < 4; ++i)
            af[i] = *(const f16x8*)&As[(wm + i * 16 + fm) * QPAD + kk * 32 + kq * 8];
#pragma unroll
        for (int j = 0; j < 4; ++j)
            bf[j] = *(const f16x8*)&Bs[(wn + j * 16 + fm) * QPAD + kk * 32 + kq * 8];
#pragma unroll
        for (int i = 0; i < 4; ++i)
#pragma unroll
            for (int j = 0; j < 4; ++j)
                acc[i][j] = __builtin_amdgcn_mfma_f32_16x16x32_f16(af[i], bf[j], acc[i][j], 0, 0, 0);
    }

#pragma unroll
    for (int i = 0; i < 4; ++i) {
#pragma unroll
        for (int j = 0; j < 4; ++j) {
            const int col = n0 + wn + j * 16 + fm;
            const int rowb = m0 + wm + i * 16 + kq * 4;
#pragma unroll
            for (int r = 0; r < 4; ++r)
                Cb[(size_t)(rowb + r) * 1024 + col] = (f16)(acc[i][j][r] + bias[col]);
        }
    }
}

// ---------------- out GEMM: 64x128 tile (256 blocks — full CU coverage) ----------------
__global__ __launch_bounds__(256) void gemm_out_kernel(
    const f16* __restrict__ A,      // ab [NPTS][512]
    const f16* __restrict__ Bt,     // bt2 [128][512]
    const float* __restrict__ bias2,
    const float* __restrict__ feat, // [NPTS][128] fp32
    float* __restrict__ CT)         // [B][DP][N]
{
    __shared__ __align__(16) f16 As[64 * 32];
    __shared__ __align__(16) f16 Bs[128 * 32];
    const int tid = threadIdx.x;
    const int m0 = blockIdx.x * 64;
    const int w = tid >> 6, l = tid & 63;
    const int wn = w * 32;
    const int fm = l & 15, kq = l >> 4;

    floatx4 acc[4][2];
#pragma unroll
    for (int i = 0; i < 4; ++i)
#pragma unroll
        for (int j = 0; j < 2; ++j)
            acc[i][j] = (floatx4){0.0f, 0.0f, 0.0f, 0.0f};

    for (int k0 = 0; k0 < 512; k0 += 32) {
        __syncthreads();
        {
            const int row = tid >> 2, part = tid & 3;
            *(uint4*)&As[row * 32 + part * 8] =
                *(const uint4*)&A[(size_t)(m0 + row) * 512 + k0 + part * 8];
        }
#pragma unroll
        for (int c = 0; c < 2; ++c) {
            const int li = tid + c * 256;
            const int row = li >> 2, part = li & 3;
            *(uint4*)&Bs[row * 32 + part * 8] =
                *(const uint4*)&Bt[(size_t)row * 512 + k0 + part * 8];
        }
        __syncthreads();
        f16x8 af[4], bf[2];
#pragma unroll
        for (int i = 0; i < 4; ++i)
            af[i] = *(const f16x8*)&As[(i * 16 + fm) * 32 + kq * 8];
#pragma unroll
        for (int j = 0; j < 2; ++j)
            bf[j] = *(const f16x8*)&Bs[(wn + j * 16 + fm) * 32 + kq * 8];
#pragma unroll
        for (int i = 0; i < 4; ++i)
#pragma unroll
            for (int j = 0; j < 2; ++j)
                acc[i][j] = __builtin_amdgcn_mfma_f32_16x16x32_f16(af[i], bf[j], acc[i][j], 0, 0, 0);
    }

#pragma unroll
    for (int i = 0; i < 4; ++i) {
#pragma unroll
        for (int j = 0; j < 2; ++j) {
            const int col = wn + j * 16 + fm;
            const int rowb = m0 + i * 16 + kq * 4;
            float4 vv;
#pragma unroll
            for (int r = 0; r < 4; ++r)
                ((float*)&vv)[r] = acc[i][j][r] + bias2[col]
                                 + feat[(size_t)(rowb + r) * DP_ + col];
            const int bb = rowb >> 12;
            *(float4*)&CT[(size_t)(bb * DP_ + col) * N_ + (rowb & (N_ - 1))] = vv;
        }
    }
}

// ---------------- kvw body: pack {k fp8, v fp8, w f16} rows + u buffer ----------------
// kvw row p = 1024 B, group g at 16*g: bytes 0-3 k fp8, 4-7 v fp8, 8-15 w f16x4.
// w = xyz[p].fd1 (no bias), u = w + fd1_b -> linear split of the positional MLP:
// h_k = relu(u_p - w_gik)  (exact algebra; only f16 rounding of u,w).
static __device__ void kvw_body(const f16* __restrict__ qkv, const float* __restrict__ xyz,
                                const float* __restrict__ fd1_w, const float* __restrict__ fd1_b,
                                u8* __restrict__ kvw, f16* __restrict__ ubuf, int id)
{
    const int t = id * 256 + threadIdx.x;   // 0 .. NPTS*64-1
    const int p = t >> 6, g = t & 63;
    const uint4 kv = *(const uint4*)(qkv + (size_t)p * 1024 + 256 + g * 8);
    const h2 k01 = ash2(kv.x), k23 = ash2(kv.y), v01 = ash2(kv.z), v23 = ash2(kv.w);
    int lo = 0, hi = 0;
    lo = __builtin_amdgcn_cvt_pk_fp8_f32((float)k01.x, (float)k01.y, lo, false);
    lo = __builtin_amdgcn_cvt_pk_fp8_f32((float)k23.x, (float)k23.y, lo, true);
    hi = __builtin_amdgcn_cvt_pk_fp8_f32((float)v01.x, (float)v01.y, hi, false);
    hi = __builtin_amdgcn_cvt_pk_fp8_f32((float)v23.x, (float)v23.y, hi, true);

    const float x0 = xyz[(size_t)p * 3 + 0];
    const float x1 = xyz[(size_t)p * 3 + 1];
    const float x2 = xyz[(size_t)p * 3 + 2];
    const int c0 = g * 4;
    const float4 w0v = *(const float4*)&fd1_w[c0];
    const float4 w1v = *(const float4*)&fd1_w[DM_ + c0];
    const float4 w2v = *(const float4*)&fd1_w[2 * DM_ + c0];
    const float4 b1v = *(const float4*)&fd1_b[c0];
    const float ww0 = x0 * w0v.x + x1 * w1v.x + x2 * w2v.x;
    const float ww1 = x0 * w0v.y + x1 * w1v.y + x2 * w2v.y;
    const float ww2 = x0 * w0v.z + x1 * w1v.z + x2 * w2v.z;
    const float ww3 = x0 * w0v.w + x1 * w1v.w + x2 * w2v.w;

    uint4 row;
    row.x = (u32)lo;
    row.y = (u32)hi;
    row.z = asu32(pkrtz(ww0, ww1));
    row.w = asu32(pkrtz(ww2, ww3));
    *(uint4*)(kvw + (size_t)p * 1024 + g * 16) = row;

    const uint2 uu = make_uint2(asu32(pkrtz(ww0 + b1v.x, ww1 + b1v.y)),
                                asu32(pkrtz(ww2 + b1v.z, ww3 + b1v.w)));
    *(uint2*)(ubuf + (size_t)p * 256 + c0) = uu;
}

static __device__ void mergeAB_body(const u32* __restrict__ part, int* __restrict__ knn_idx,
                                    int id)
{
    const int p = id * 256 + threadIdx.x;
    const int b = p >> 12;

    u32 L[16];
#pragma unroll
    for (int i = 0; i < 16; ++i) L[i] = 0xFFFFFFFFu;

    for (int s = 0; s < SEG_; ++s) {
        u32 seg[16];
#pragma unroll
        for (int j = 0; j < 16; ++j)
            seg[j] = part[(size_t)(s * 16 + j) * NPTS + p];
#pragma unroll
        for (int i = 0; i < 16; ++i) L[i] = min(L[i], seg[15 - i]);
        remerge16_asc(L);
    }

    int* o = knn_idx + (size_t)p * K_;
#pragma unroll
    for (int i = 0; i < 16; ++i) o[i] = b * N_ + (int)(L[i] & 0xFFFu);
}

__global__ __launch_bounds__(256) void fused_kvwmerge_kernel(
    const f16* __restrict__ qkv, const float* __restrict__ xyz,
    const float* __restrict__ fd1_w, const float* __restrict__ fd1_b,
    u8* __restrict__ kvw, f16* __restrict__ ubuf,
    const u32* __restrict__ part, int* __restrict__ knn_idx)
{
    const int id = blockIdx.x;
    if (id < NPTS * 64 / 256) kvw_body(qkv, xyz, fd1_w, fd1_b, kvw, ubuf, id);
    else                      mergeAB_body(part, knn_idx, id - NPTS * 64 / 256);
}

// ---------------- fused small GEMMs 1: wqp (4 tiles) + bt2 (2 tiles) ----------------
__global__ __launch_bounds__(256) void fused_small1_kernel(
    const f16* __restrict__ fd2c, const f16* __restrict__ wqc,
    f16* __restrict__ catWqp,
    const f16* __restrict__ fc2T, f16* __restrict__ bt2)
{
    __shared__ __align__(16) f16 As[128 * 32];
    __shared__ __align__(16) f16 Bs[128 * 32];
    const int id = blockIdx.x;
    if (id < 4)
        gemm_tile(As, Bs, fd2c, wqc, catWqp, DM_, DM_, DM_, DM_, id & 1, id >> 1);
    else
        gemm_tile(As, Bs, fc2T, fd2c, bt2, DP_, DM_, DM_, 512, id - 4, 0);
}

// ---------------- fused small GEMMs 2: WallT (8 tiles) + folded biases (5 blocks) ----------------
__global__ __launch_bounds__(256) void fused_small2_kernel(
    const f16* __restrict__ catW, const f16* __restrict__ fc1c, f16* __restrict__ WallT,
    const float* __restrict__ fc1_b, const float* __restrict__ fd2_b,
    const float* __restrict__ fc2_w, const float* __restrict__ fc2_b,
    float* __restrict__ b_all, float* __restrict__ bias2)
{
    __shared__ __align__(16) f16 As[128 * 32];
    __shared__ __align__(16) f16 Bs[128 * 32];
    const int id = blockIdx.x;
    const int tid = threadIdx.x;
    if (id < 8) {
        gemm_tile(As, Bs, catW, fc1c, WallT, 1024, DP_, DM_, DP_, 0, id);
    } else if (id < 12) {
        const int n = (id - 8) * 256 + tid;
        float s = 0.0f;
        for (int j = 0; j < DM_; ++j)
            s += fc1_b[j] * (float)catW[(size_t)n * DM_ + j];
        b_all[n] = s;
    } else if (tid < DP_) {
        float s = fc2_b[tid];
        for (int t = 0; t < DM_; ++t)
            s += fd2_b[t] * fc2_w[(size_t)t * DP_ + tid];
        bias2[tid] = s;
    }
}

// ---------------- fused attention: linear-split MLP, packed f16 h, 16B uint4 gathers ----
__global__ __launch_bounds__(256, 1) void attn_kernel(
    const f16* __restrict__ qkv, const u8* __restrict__ kvw,
    const f16* __restrict__ ubuf, const int* __restrict__ knn_idx,
    const float* __restrict__ fd2_b,
    f16* __restrict__ ab)
{
    const int wave = threadIdx.x >> 6, l = threadIdx.x & 63;
    const int bi = blockIdx.x;
    const int p = ((bi & 3) << 12) + ((bi >> 2) << 2) + wave;   // batch-pinned remap
    const int c0 = l * 4;

    int gi = 0;
    if (l < 16) gi = knn_idx[p * K_ + l];

    // prefetch ALL 16 neighbor kvw rows (independent 16B loads), pin above compute
    uint4 kvr[16];
#pragma unroll
    for (int k = 0; k < 16; ++k) {
        const int gik = __shfl(gi, k);
        kvr[k] = *(const uint4*)(kvw + (size_t)gik * 1024 + l * 16);
    }
    asm volatile("" ::: "memory");

    const uint2 qu  = *(const uint2*)(qkv + (size_t)p * 1024 + c0);
    const uint2 qpu = *(const uint2*)(qkv + (size_t)p * 1024 + 768 + c0);
    const uint2 uu  = *(const uint2*)(ubuf + (size_t)p * 256 + c0);
    const h2 qh01 = ash2(qu.x), qh23 = ash2(qu.y);
    const h2 qp01 = ash2(qpu.x), qp23 = ash2(qpu.y);
    const h2 u01 = ash2(uu.x), u23 = ash2(uu.y);
    const float q0 = (float)qh01.x, q1 = (float)qh01.y, q2 = (float)qh23.x, q3 = (float)qh23.y;
    const h2 zero2 = (h2)(__fp16)0.0f;

    const float4 f2b = *(const float4*)&fd2_b[c0];

    // qb = q . fd2_b (constant over k)
    float qb;
    {
        float tq = q0 * f2b.x + q1 * f2b.y + q2 * f2b.z + q3 * f2b.w;
#pragma unroll
        for (int off = 1; off < 64; off <<= 1) tq += __shfl_xor(tq, off);
        qb = tq;
    }

    // phase 1: h = pk_max(u - w, 0) (2 packed ops per 4 dims); logits via dot2
    float lg[16];
    u32 h01r[16], h23r[16];
#pragma unroll
    for (int k = 0; k < 16; ++k) {
        const uint4 r = kvr[k];
        h2 d01 = u01 - ash2(r.z);
        h2 d23 = u23 - ash2(r.w);
        d01 = __builtin_elementwise_max(d01, zero2);
        d23 = __builtin_elementwise_max(d23, zero2);
        h01r[k] = asu32(d01); h23r[k] = asu32(d23);
        const auto k01 = __builtin_amdgcn_cvt_pk_f32_fp8((int)r.x, false);
        const auto k23 = __builtin_amdgcn_cvt_pk_f32_fp8((int)r.x, true);
        float t = q0 * k01[0] + q1 * k01[1] + q2 * k23[0] + q3 * k23[1];
        t = __builtin_amdgcn_fdot2(d01, qp01, t, false);
        t = __builtin_amdgcn_fdot2(d23, qp23, t, false);
#pragma unroll
        for (int off = 1; off < 64; off <<= 1) t += __shfl_xor(t, off);
        lg[k] = t;
    }

    // softmax over 16 (redundant per lane, all registers)
    float att[16];
    {
        float mx = -3.0e38f;
#pragma unroll
        for (int k = 0; k < 16; ++k) {
            att[k] = (lg[k] + qb) * (1.0f / 16.0f);
            mx = fmaxf(mx, att[k]);
        }
        float s = 0.0f;
#pragma unroll
        for (int k = 0; k < 16; ++k) { att[k] = __expf(att[k] - mx); s += att[k]; }
        const float inv = 1.0f / s;
#pragma unroll
        for (int k = 0; k < 16; ++k) att[k] *= inv;
    }

    // phase 2: pure VALU — rbar = sum att*v (kvr regs), hbar = sum att*h (regs)
    float rb[4] = {0, 0, 0, 0}, hb[4] = {0, 0, 0, 0};
#pragma unroll
    for (int k = 0; k < 16; ++k) {
        const auto v01 = __builtin_amdgcn_cvt_pk_f32_fp8((int)kvr[k].y, false);
        const auto v23 = __builtin_amdgcn_cvt_pk_f32_fp8((int)kvr[k].y, true);
        const h2 hh01 = ash2(h01r[k]), hh23 = ash2(h23r[k]);
        const float a = att[k];
        rb[0] = fmaf(a, v01[0], rb[0]);
        rb[1] = fmaf(a, v01[1], rb[1]);
        rb[2] = fmaf(a, v23[0], rb[2]);
        rb[3] = fmaf(a, v23[1], rb[3]);
        hb[0] = fmaf(a, (float)hh01.x, hb[0]);
        hb[1] = fmaf(a, (float)hh01.y, hb[1]);
        hb[2] = fmaf(a, (float)hh23.x, hb[2]);
        hb[3] = fmaf(a, (float)hh23.y, hb[3]);
    }

    const uint2 ho = make_uint2(asu32(pkrtz(hb[0], hb[1])), asu32(pkrtz(hb[2], hb[3])));
    const uint2 ro = make_uint2(asu32(pkrtz(rb[0], rb[1])), asu32(pkrtz(rb[2], rb[3])));
    *(uint2*)(ab + (size_t)p * 512 + c0) = ho;
    *(uint2*)(ab + (size_t)p * 512 + 256 + c0) = ro;
}

extern "C" void kernel_launch(void* const* d_in, const int* in_sizes, int n_in,
                              void* d_out, int out_size, void* d_ws, size_t ws_size,
                              hipStream_t stream)
{
    const float* features = (const float*)d_in[0];
    const float* xyz   = (const float*)d_in[1];
    const float* fc1_w = (const float*)d_in[2];
    const float* fc1_b = (const float*)d_in[3];
    const float* fc2_w = (const float*)d_in[4];
    const float* fc2_b = (const float*)d_in[5];
    const float* fd1_w = (const float*)d_in[6];
    const float* fd1_b = (const float*)d_in[7];
    const float* fd2_w = (const float*)d_in[8];
    const float* fd2_b = (const float*)d_in[9];
    const float* wq    = (const float*)d_in[10];
    const float* wk    = (const float*)d_in[11];
    const float* wv    = (const float*)d_in[12];
    float* out = (float*)d_out;

    char* base = (char*)d_ws;
    const size_t MB = 1024 * 1024;
    u32*  part = (u32*)(base + 0);                 // 16 MB (16 segs), dead after merge
    f16*  ab   = (f16*)(base + 0);                 // 16 MB [hbar|rbar]
    u8*   kvw  = (u8*)(base + 20 * MB);            // 16 MB {k fp8, v fp8, w f16} rows
    f16*  qkv  = (f16*)(base + 36 * MB);           // 32 MB
    f16*  featb = (f16*)(base + 68 * MB);          // 4 MB
    int*  idx  = (int*)(base + 72 * MB);           // 1 MB
    char* wb = base + 73 * MB;
    f16* catW  = (f16*)(wb + 0);                   // 512 KB
    f16* WallT = (f16*)(wb + 512 * 1024);          // 256 KB
    f16* bt2   = (f16*)(wb + 768 * 1024);          // 128 KB
    f16* fd2c  = (f16*)(wb + 896 * 1024);
    f16* wqc   = (f16*)(wb + 1024 * 1024);
    f16* fc1c  = (f16*)(wb + 1152 * 1024);
    f16* fc2T  = (f16*)(wb + 1216 * 1024);
    float* b_all = (float*)(wb + 1280 * 1024);
    float* bias2 = (float*)(wb + 1284 * 1024);
    f16*  ubuf = (f16*)(base + 76 * MB);           // 8 MB u = xyz.fd1 + b (f16)

    const dim3 blk(256);

    // 1. prep casts (512 blocks) || KNN partial top-16 (1024 blocks)
    fused_prep_knn_kernel<<<dim3(512 + 1024), blk, 0, stream>>>(
        wq, wk, wv, fd2_w, fc1_w, fc2_w, features,
        catW, fc2T, bt2, fd2c, wqc, fc1c, featb, xyz, part);
    // 2. wqp -> catW rows 768.. (4 tiles) || bt2 cols [0,256) (2 tiles)
    fused_small1_kernel<<<dim3(6), blk, 0, stream>>>(fd2c, wqc, catW + 768 * 256, fc2T, bt2);
    // 3. WallT (8 tiles) || b_all (4) || bias2 (1)
    fused_small2_kernel<<<dim3(13), blk, 0, stream>>>(catW, fc1c, WallT,
                                                      fc1_b, fd2_b, fc2_w, fc2_b, b_all, bias2);
    // 4. [q | kv-interleaved | qp] = features @ WallT^T + b_all  (K=128, single-barrier)
    gemm_qkv_kernel<<<dim3(1024 / 128, NPTS / 128), blk, 0, stream>>>(featb, WallT, b_all, qkv);
    // 5. kvw pack + u buffer (4096 blocks) || 16-segment merge (64 blocks)
    fused_kvwmerge_kernel<<<dim3(NPTS * 64 / 256 + NPTS / 256), blk, 0, stream>>>(
        qkv, xyz, fd1_w, fd1_b, kvw, ubuf, part, idx);
    // 6. fused attention -> ab = [hbar | rbar]  (XCD batch-pinned block remap)
    attn_kernel<<<dim3(NPTS / 4), blk, 0, stream>>>(qkv, kvw, ubuf, idx, fd2_b, ab);
    // 7. out GEMM: 64x128 tiles -> 256 blocks, fused transpose + bias + residual
    gemm_out_kernel<<<dim3(NPTS / 64), blk, 0, stream>>>(ab, bt2, bias2, features, out);

    (void)in_sizes; (void)n_in; (void)out_size; (void)ws_size;
}